// Round 10
// baseline (186.299 us; speedup 1.0000x reference)
//
#include <hip/hip_runtime.h>

#define F0 128
#define F1 64
#define F2 32

typedef unsigned short ushort_t;
typedef unsigned int uint_t;

__device__ __forceinline__ ushort_t f2bf(float f) {   // f32 -> bf16 RNE
    uint_t u = __float_as_uint(f);
    return (ushort_t)((u + 0x7FFFu + ((u >> 16) & 1u)) >> 16);
}
__device__ __forceinline__ float bf2f(ushort_t u) {   // bf16 -> f32
    return __uint_as_float((uint_t)u << 16);
}

// ================= CSR build =================
__global__ void zero_cnt(int* __restrict__ cnt, int N) {
    int i = blockIdx.x * 256 + threadIdx.x;
    if (i < N) cnt[i] = 0;
}

// XCD-partitioned histogram: block b only counts cols in range (b&7) ->
// each cnt line has a single L2 owner (same trick as edge_fill, r8 win).
__global__ void count_deg(const int* __restrict__ col, int* cnt, int E, int cpx) {
    int x = blockIdx.x & 7;
    int lo = x * cpx, hi = lo + cpx;
    int stride = (gridDim.x >> 3) * 256;
    for (int e = (blockIdx.x >> 3) * 256 + threadIdx.x; e < E; e += stride) {
        int c = col[e];
        if (c >= lo && c < hi) atomicAdd(&cnt[c], 1);
    }
}

__global__ void scan_partial(const int* __restrict__ cnt, int* __restrict__ partial, int N) {
    __shared__ int red[256];
    int i = blockIdx.x * 256 + threadIdx.x;
    red[threadIdx.x] = (i < N) ? cnt[i] : 0;
    __syncthreads();
    for (int off = 128; off; off >>= 1) {
        if (threadIdx.x < off) red[threadIdx.x] += red[threadIdx.x + off];
        __syncthreads();
    }
    if (threadIdx.x == 0) partial[blockIdx.x] = red[0];
}

__global__ __launch_bounds__(1024) void scan_block(int* partial, int nb) {
    __shared__ int s[1024];
    int t = threadIdx.x;
    int v = (t < nb) ? partial[t] : 0;
    s[t] = v;
    __syncthreads();
    for (int off = 1; off < 1024; off <<= 1) {
        int u = (t >= off) ? s[t - off] : 0;
        __syncthreads();
        s[t] += u;
        __syncthreads();
    }
    if (t < nb) partial[t] = s[t] - v;
}

// cur may alias cnt: each element read once before any write.
__global__ void scan_final(const int* __restrict__ cnt, const int* __restrict__ partial,
                           int* __restrict__ ptr, int* __restrict__ cur,
                           float* __restrict__ dinv, int N, int E) {
    __shared__ int s[256];
    int t = threadIdx.x;
    int i = blockIdx.x * 256 + t;
    int v = (i < N) ? cnt[i] : 0;
    s[t] = v;
    __syncthreads();
    for (int off = 1; off < 256; off <<= 1) {
        int u = (t >= off) ? s[t - off] : 0;
        __syncthreads();
        s[t] += u;
        __syncthreads();
    }
    if (i < N) {
        int p = partial[blockIdx.x] + s[t] - v;
        ptr[i] = p;
        cur[i] = p;
        dinv[i] = rsqrtf((float)(v + 1));
    } else if (i == N) {
        ptr[N] = E;
    }
}

// XCD-partitioned counting-sort fill (r8 win: single-owner erow lines).
__global__ void edge_fill(const int* __restrict__ row, const int* __restrict__ col,
                          int* cur, int* __restrict__ erow, int E, int cpx) {
    int x = blockIdx.x & 7;
    int lo = x * cpx, hi = lo + cpx;
    int nchunks = gridDim.x >> 3;
    int stride = nchunks * 256;
    for (int e = (blockIdx.x >> 3) * 256 + threadIdx.x; e < E; e += stride) {
        int c = col[e];
        if (c >= lo && c < hi) {
            int pos = atomicAdd(&cur[c], 1);
            erow[pos] = row[e];
        }
    }
}

// ================= register-tiled GEMM 1 =================
__device__ __forceinline__ void fma4(float4& a, float xs, const float4& wv) {
    a.x = fmaf(xs, wv.x, a.x);
    a.y = fmaf(xs, wv.y, a.y);
    a.z = fmaf(xs, wv.z, a.z);
    a.w = fmaf(xs, wv.w, a.w);
}

// gemm1: xwb = (x @ W1) * dinv[row], stored bf16. tile 64x64, thread = 4x4.
__global__ __launch_bounds__(256) void gemm1(const float* __restrict__ x,
                                             const float* __restrict__ W,
                                             const float* __restrict__ dinv,
                                             ushort_t* __restrict__ xwb, int N) {
    __shared__ float Xl[64 * F0];   // 32KB, swizzled
    __shared__ float Wl[F0 * F1];   // 32KB, linear [k][64]
    int tid = threadIdx.x;
    int base = blockIdx.x * 64;

    const float4* W4 = (const float4*)W;
    float4* Wl4 = (float4*)Wl;
#pragma unroll
    for (int i = 0; i < 8; ++i) Wl4[tid + 256 * i] = W4[tid + 256 * i];

    float4* Xl4 = (float4*)Xl;
#pragma unroll
    for (int i = 0; i < 8; ++i) {
        int idx = tid + 256 * i;
        int r = idx >> 5, c4 = idx & 31;
        int gr = base + r;
        float4 v = (gr < N) ? ((const float4*)x)[(size_t)gr * 32 + c4]
                            : make_float4(0.f, 0.f, 0.f, 0.f);
        Xl4[r * 32 + (c4 ^ (r >> 2))] = v;
    }
    __syncthreads();

    int tc = tid & 15, tr = tid >> 4;
    float4 acc0 = make_float4(0.f, 0.f, 0.f, 0.f);
    float4 acc1 = acc0, acc2 = acc0, acc3 = acc0;
    const float4* Wl4c = (const float4*)Wl;
    const float4* Xl4c = (const float4*)Xl;

#pragma unroll 4
    for (int kk = 0; kk < 32; ++kk) {
        float4 xv0 = Xl4c[(4 * tr + 0) * 32 + (kk ^ tr)];
        float4 xv1 = Xl4c[(4 * tr + 1) * 32 + (kk ^ tr)];
        float4 xv2 = Xl4c[(4 * tr + 2) * 32 + (kk ^ tr)];
        float4 xv3 = Xl4c[(4 * tr + 3) * 32 + (kk ^ tr)];
        float4 w0 = Wl4c[(4 * kk + 0) * 16 + tc];
        float4 w1 = Wl4c[(4 * kk + 1) * 16 + tc];
        float4 w2 = Wl4c[(4 * kk + 2) * 16 + tc];
        float4 w3 = Wl4c[(4 * kk + 3) * 16 + tc];
        fma4(acc0, xv0.x, w0); fma4(acc0, xv0.y, w1); fma4(acc0, xv0.z, w2); fma4(acc0, xv0.w, w3);
        fma4(acc1, xv1.x, w0); fma4(acc1, xv1.y, w1); fma4(acc1, xv1.z, w2); fma4(acc1, xv1.w, w3);
        fma4(acc2, xv2.x, w0); fma4(acc2, xv2.y, w1); fma4(acc2, xv2.z, w2); fma4(acc2, xv2.w, w3);
        fma4(acc3, xv3.x, w0); fma4(acc3, xv3.y, w1); fma4(acc3, xv3.z, w2); fma4(acc3, xv3.w, w3);
    }

    int gr = base + 4 * tr;
#pragma unroll
    for (int k = 0; k < 4; ++k) {
        int r = gr + k;
        if (r < N) {
            float d = dinv[r];
            float4 a = (k == 0) ? acc0 : (k == 1) ? acc1 : (k == 2) ? acc2 : acc3;
            ushort4 o = make_ushort4(f2bf(a.x * d), f2bf(a.y * d), f2bf(a.z * d), f2bf(a.w * d));
            *(ushort4*)(&xwb[(size_t)r * F1 + 4 * tc]) = o;
        }
    }
}

// ================= fused layer-1 aggregation + layer-2 projection =================
// One wave per node: gather layer-1 row (64 lanes), h = relu(acc*dinv+b1),
// then in-wave h @ W2 (64->32) via shfl broadcast, write hwb = bf16(h2w*dinv).
__global__ __launch_bounds__(256) void agg1_g2(const int* __restrict__ ptr,
                                               const int* __restrict__ erow,
                                               const ushort_t* __restrict__ xwb,
                                               const float* __restrict__ dinv,
                                               const float* __restrict__ b1,
                                               const float* __restrict__ W2,
                                               ushort_t* __restrict__ hwb, int N) {
    __shared__ float W2l[F1 * F2];  // 8KB
    for (int idx = threadIdx.x; idx < F1 * F2; idx += 256) W2l[idx] = W2[idx];
    __syncthreads();

    int t = blockIdx.x * 256 + threadIdx.x;
    int i = t >> 6, j = t & 63;
    if (i >= N) return;

    float acc = bf2f(xwb[(size_t)i * F1 + j]);   // scaled self term
    int e = ptr[i], end = ptr[i + 1];
    for (; e + 3 < end; e += 4) {
        int r0 = erow[e], r1 = erow[e + 1], r2 = erow[e + 2], r3 = erow[e + 3];
        float v0 = bf2f(xwb[(size_t)r0 * F1 + j]);
        float v1 = bf2f(xwb[(size_t)r1 * F1 + j]);
        float v2 = bf2f(xwb[(size_t)r2 * F1 + j]);
        float v3 = bf2f(xwb[(size_t)r3 * F1 + j]);
        acc += v0; acc += v1; acc += v2; acc += v3;
    }
    for (; e < end; ++e) acc += bf2f(xwb[(size_t)erow[e] * F1 + j]);

    float h = fmaxf(acc * dinv[i] + b1[j], 0.0f);   // layer-1 output element j

    // in-wave 64->32 projection: lane j computes partial for col (j&31) over
    // k-half (j>>5); shfl broadcasts h_k across the wave.
    int half = j >> 5, j2 = j & 31;
    int kbase = half * 32;
    float p = 0.0f;
#pragma unroll 8
    for (int k = 0; k < 32; ++k) {
        float hk = __shfl(h, kbase + k, 64);
        p = fmaf(hk, W2l[(kbase + k) * F2 + j2], p);
    }
    p += __shfl_down(p, 32, 64);   // combine the two k-halves into lanes 0..31
    if (j < 32) hwb[(size_t)i * F2 + j] = f2bf(p * dinv[i]);
}

// ================= layer 2 aggregation + fused log_softmax =================
__global__ void agg2_lsm(const int* __restrict__ ptr, const int* __restrict__ erow,
                         const ushort_t* __restrict__ hwb, const float* __restrict__ dinv,
                         const float* __restrict__ b, float* __restrict__ out, int N) {
    int t = blockIdx.x * 256 + threadIdx.x;
    int i = t >> 5, j = t & 31;
    if (i >= N) return;
    float acc = bf2f(hwb[(size_t)i * F2 + j]);
    int e = ptr[i], end = ptr[i + 1];
    for (; e + 3 < end; e += 4) {
        int r0 = erow[e], r1 = erow[e + 1], r2 = erow[e + 2], r3 = erow[e + 3];
        float v0 = bf2f(hwb[(size_t)r0 * F2 + j]);
        float v1 = bf2f(hwb[(size_t)r1 * F2 + j]);
        float v2 = bf2f(hwb[(size_t)r2 * F2 + j]);
        float v3 = bf2f(hwb[(size_t)r3 * F2 + j]);
        acc += v0; acc += v1; acc += v2; acc += v3;
    }
    for (; e < end; ++e) acc += bf2f(hwb[(size_t)erow[e] * F2 + j]);
    acc = acc * dinv[i] + b[j];
    float m = acc;
    for (int off = 16; off; off >>= 1) m = fmaxf(m, __shfl_xor(m, off, 32));
    float s = expf(acc - m);
    for (int off = 16; off; off >>= 1) s += __shfl_xor(s, off, 32);
    out[(size_t)i * F2 + j] = acc - m - logf(s);
}

extern "C" void kernel_launch(void* const* d_in, const int* in_sizes, int n_in,
                              void* d_out, int out_size, void* d_ws, size_t ws_size,
                              hipStream_t stream) {
    const float* x  = (const float*)d_in[0];
    const int*   ei = (const int*)d_in[1];
    const float* W1 = (const float*)d_in[2];
    const float* b1 = (const float*)d_in[3];
    const float* W2 = (const float*)d_in[4];
    const float* b2 = (const float*)d_in[5];

    int N = in_sizes[0] / F0;
    int E = in_sizes[1] / 2;
    const int* row = ei;
    const int* col = ei + E;

    size_t Np = ((size_t)N + 63) & ~(size_t)63;
    size_t Ep = ((size_t)E + 63) & ~(size_t)63;
    int*      cnt     = (int*)d_ws;                  // Np (reused as cur)
    int*      ptr     = cnt + Np;                    // Np+64
    float*    dinv    = (float*)(ptr + Np + 64);     // Np
    int*      partial = (int*)(dinv + Np);           // 1024
    int*      erow    = partial + 1024;              // Ep
    ushort_t* xwb     = (ushort_t*)(erow + Ep);      // Np*64 bf16
    ushort_t* hwb     = xwb + Np * F1;               // Np*32 bf16 (must NOT alias xwb)
    int*      cur     = cnt;
    float*    out2    = (float*)d_out;

    int nbN  = (N + 255) / 256;
    int nbN1 = (N + 256) / 256;
    int cpx  = (N + 7) / 8;   // cols per XCD range

    zero_cnt<<<nbN, 256, 0, stream>>>(cnt, N);
    count_deg<<<256 * 8, 256, 0, stream>>>(col, cnt, E, cpx);
    scan_partial<<<nbN, 256, 0, stream>>>(cnt, partial, N);
    scan_block<<<1, 1024, 0, stream>>>(partial, nbN);
    scan_final<<<nbN1, 256, 0, stream>>>(cnt, partial, ptr, cur, dinv, N, E);
    edge_fill<<<256 * 8, 256, 0, stream>>>(row, col, cur, erow, E, cpx);

    gemm1<<<(N + 63) / 64, 256, 0, stream>>>(x, W1, dinv, xwb, N);
    agg1_g2<<<(int)(((size_t)N * F1 + 255) / 256), 256, 0, stream>>>(ptr, erow, xwb, dinv, b1, W2, hwb, N);
    agg2_lsm<<<(int)(((size_t)N * F2 + 255) / 256), 256, 0, stream>>>(ptr, erow, hwb, dinv, b2, out2, N);
}

// Round 11
// 177.901 us; speedup vs baseline: 1.0472x; 1.0472x over previous
//
#include <hip/hip_runtime.h>

#define F0 128
#define F1 64
#define F2 32

typedef unsigned short ushort_t;
typedef unsigned int uint_t;

__device__ __forceinline__ ushort_t f2bf(float f) {   // f32 -> bf16 RNE
    uint_t u = __float_as_uint(f);
    return (ushort_t)((u + 0x7FFFu + ((u >> 16) & 1u)) >> 16);
}
__device__ __forceinline__ float bf2f(ushort_t u) {   // bf16 -> f32
    return __uint_as_float((uint_t)u << 16);
}

// ================= CSR build =================
__global__ void zero_cnt(int* __restrict__ cnt, int N) {
    int i = blockIdx.x * 256 + threadIdx.x;
    if (i < N) cnt[i] = 0;
}

// XCD-partitioned histogram: block b only counts cols in range (b&7) ->
// single L2 owner per cnt line (r9/r10: ~10us faster than naive).
__global__ void count_deg(const int* __restrict__ col, int* cnt, int E, int cpx) {
    int x = blockIdx.x & 7;
    int lo = x * cpx, hi = lo + cpx;
    int stride = (gridDim.x >> 3) * 256;
    for (int e = (blockIdx.x >> 3) * 256 + threadIdx.x; e < E; e += stride) {
        int c = col[e];
        if (c >= lo && c < hi) atomicAdd(&cnt[c], 1);
    }
}

__global__ void scan_partial(const int* __restrict__ cnt, int* __restrict__ partial, int N) {
    __shared__ int red[256];
    int i = blockIdx.x * 256 + threadIdx.x;
    red[threadIdx.x] = (i < N) ? cnt[i] : 0;
    __syncthreads();
    for (int off = 128; off; off >>= 1) {
        if (threadIdx.x < off) red[threadIdx.x] += red[threadIdx.x + off];
        __syncthreads();
    }
    if (threadIdx.x == 0) partial[blockIdx.x] = red[0];
}

__global__ __launch_bounds__(1024) void scan_block(int* partial, int nb) {
    __shared__ int s[1024];
    int t = threadIdx.x;
    int v = (t < nb) ? partial[t] : 0;
    s[t] = v;
    __syncthreads();
    for (int off = 1; off < 1024; off <<= 1) {
        int u = (t >= off) ? s[t - off] : 0;
        __syncthreads();
        s[t] += u;
        __syncthreads();
    }
    if (t < nb) partial[t] = s[t] - v;
}

// cur may alias cnt: each element read once before any write.
__global__ void scan_final(const int* __restrict__ cnt, const int* __restrict__ partial,
                           int* __restrict__ ptr, int* __restrict__ cur,
                           float* __restrict__ dinv, int N, int E) {
    __shared__ int s[256];
    int t = threadIdx.x;
    int i = blockIdx.x * 256 + t;
    int v = (i < N) ? cnt[i] : 0;
    s[t] = v;
    __syncthreads();
    for (int off = 1; off < 256; off <<= 1) {
        int u = (t >= off) ? s[t - off] : 0;
        __syncthreads();
        s[t] += u;
        __syncthreads();
    }
    if (i < N) {
        int p = partial[blockIdx.x] + s[t] - v;
        ptr[i] = p;
        cur[i] = p;
        dinv[i] = rsqrtf((float)(v + 1));
    } else if (i == N) {
        ptr[N] = E;
    }
}

// XCD-partitioned counting-sort fill (r8 win: single-owner erow lines).
__global__ void edge_fill(const int* __restrict__ row, const int* __restrict__ col,
                          int* cur, int* __restrict__ erow, int E, int cpx) {
    int x = blockIdx.x & 7;
    int lo = x * cpx, hi = lo + cpx;
    int nchunks = gridDim.x >> 3;
    int stride = nchunks * 256;
    for (int e = (blockIdx.x >> 3) * 256 + threadIdx.x; e < E; e += stride) {
        int c = col[e];
        if (c >= lo && c < hi) {
            int pos = atomicAdd(&cur[c], 1);
            erow[pos] = row[e];
        }
    }
}

// ================= register-tiled GEMMs =================
__device__ __forceinline__ void fma4(float4& a, float xs, const float4& wv) {
    a.x = fmaf(xs, wv.x, a.x);
    a.y = fmaf(xs, wv.y, a.y);
    a.z = fmaf(xs, wv.z, a.z);
    a.w = fmaf(xs, wv.w, a.w);
}

// gemm1: xwb = (x @ W1) * dinv[row], stored bf16. tile 64x64, thread = 4x4.
__global__ __launch_bounds__(256) void gemm1(const float* __restrict__ x,
                                             const float* __restrict__ W,
                                             const float* __restrict__ dinv,
                                             ushort_t* __restrict__ xwb, int N) {
    __shared__ float Xl[64 * F0];   // 32KB, swizzled
    __shared__ float Wl[F0 * F1];   // 32KB, linear [k][64]
    int tid = threadIdx.x;
    int base = blockIdx.x * 64;

    const float4* W4 = (const float4*)W;
    float4* Wl4 = (float4*)Wl;
#pragma unroll
    for (int i = 0; i < 8; ++i) Wl4[tid + 256 * i] = W4[tid + 256 * i];

    float4* Xl4 = (float4*)Xl;
#pragma unroll
    for (int i = 0; i < 8; ++i) {
        int idx = tid + 256 * i;
        int r = idx >> 5, c4 = idx & 31;
        int gr = base + r;
        float4 v = (gr < N) ? ((const float4*)x)[(size_t)gr * 32 + c4]
                            : make_float4(0.f, 0.f, 0.f, 0.f);
        Xl4[r * 32 + (c4 ^ (r >> 2))] = v;
    }
    __syncthreads();

    int tc = tid & 15, tr = tid >> 4;
    float4 acc0 = make_float4(0.f, 0.f, 0.f, 0.f);
    float4 acc1 = acc0, acc2 = acc0, acc3 = acc0;
    const float4* Wl4c = (const float4*)Wl;
    const float4* Xl4c = (const float4*)Xl;

#pragma unroll 4
    for (int kk = 0; kk < 32; ++kk) {
        float4 xv0 = Xl4c[(4 * tr + 0) * 32 + (kk ^ tr)];
        float4 xv1 = Xl4c[(4 * tr + 1) * 32 + (kk ^ tr)];
        float4 xv2 = Xl4c[(4 * tr + 2) * 32 + (kk ^ tr)];
        float4 xv3 = Xl4c[(4 * tr + 3) * 32 + (kk ^ tr)];
        float4 w0 = Wl4c[(4 * kk + 0) * 16 + tc];
        float4 w1 = Wl4c[(4 * kk + 1) * 16 + tc];
        float4 w2 = Wl4c[(4 * kk + 2) * 16 + tc];
        float4 w3 = Wl4c[(4 * kk + 3) * 16 + tc];
        fma4(acc0, xv0.x, w0); fma4(acc0, xv0.y, w1); fma4(acc0, xv0.z, w2); fma4(acc0, xv0.w, w3);
        fma4(acc1, xv1.x, w0); fma4(acc1, xv1.y, w1); fma4(acc1, xv1.z, w2); fma4(acc1, xv1.w, w3);
        fma4(acc2, xv2.x, w0); fma4(acc2, xv2.y, w1); fma4(acc2, xv2.z, w2); fma4(acc2, xv2.w, w3);
        fma4(acc3, xv3.x, w0); fma4(acc3, xv3.y, w1); fma4(acc3, xv3.z, w2); fma4(acc3, xv3.w, w3);
    }

    int gr = base + 4 * tr;
#pragma unroll
    for (int k = 0; k < 4; ++k) {
        int r = gr + k;
        if (r < N) {
            float d = dinv[r];
            float4 a = (k == 0) ? acc0 : (k == 1) ? acc1 : (k == 2) ? acc2 : acc3;
            ushort4 o = make_ushort4(f2bf(a.x * d), f2bf(a.y * d), f2bf(a.z * d), f2bf(a.w * d));
            *(ushort4*)(&xwb[(size_t)r * F1 + 4 * tc]) = o;
        }
    }
}

// ================= layer 1 aggregation: one wave per node =================
// h1b[i] = bf16( relu( dinv[i]*(scaled[i] + sum_e scaled[row_e]) + b1 ) )
__global__ void agg1(const int* __restrict__ ptr, const int* __restrict__ erow,
                     const ushort_t* __restrict__ xwb, const float* __restrict__ dinv,
                     const float* __restrict__ b, ushort_t* __restrict__ h1b, int N) {
    int t = blockIdx.x * 256 + threadIdx.x;
    int i = t >> 6, j = t & 63;
    if (i >= N) return;
    float acc = bf2f(xwb[(size_t)i * F1 + j]);   // scaled self term
    int e = ptr[i], end = ptr[i + 1];
    for (; e + 3 < end; e += 4) {
        int r0 = erow[e], r1 = erow[e + 1], r2 = erow[e + 2], r3 = erow[e + 3];
        float v0 = bf2f(xwb[(size_t)r0 * F1 + j]);
        float v1 = bf2f(xwb[(size_t)r1 * F1 + j]);
        float v2 = bf2f(xwb[(size_t)r2 * F1 + j]);
        float v3 = bf2f(xwb[(size_t)r3 * F1 + j]);
        acc += v0; acc += v1; acc += v2; acc += v3;
    }
    for (; e < end; ++e) acc += bf2f(xwb[(size_t)erow[e] * F1 + j]);
    h1b[(size_t)i * F1 + j] = f2bf(fmaxf(acc * dinv[i] + b[j], 0.0f));
}

// gemm2: hwb = (h1b @ W2) * dinv[row], bf16 in / bf16 out. tile 128x32, 4x4.
__global__ __launch_bounds__(256) void gemm2(const ushort_t* __restrict__ h1b,
                                             const float* __restrict__ W,
                                             const float* __restrict__ dinv,
                                             ushort_t* __restrict__ hwb, int N) {
    __shared__ float Hl[128 * F1];  // 32KB, swizzled
    __shared__ float Wl[F1 * F2];   // 8KB
    int tid = threadIdx.x;
    int base = blockIdx.x * 128;

    const float4* W4 = (const float4*)W;
    float4* Wl4 = (float4*)Wl;
#pragma unroll
    for (int i = 0; i < 2; ++i) Wl4[tid + 256 * i] = W4[tid + 256 * i];

    // stage bf16 rows -> f32 LDS (swizzled). 8192 elems = 1024 x uint4(8 bf16).
    const uint4* H4 = (const uint4*)h1b;
    float4* Hl4 = (float4*)Hl;
#pragma unroll
    for (int it = 0; it < 4; ++it) {
        int g = tid + 256 * it;          // 0..1023
        int r = g >> 3, c8 = g & 7;      // row 0..127, 8-elem group 0..7
        int gr = base + r;
        uint4 v = (gr < N) ? H4[(size_t)gr * 8 + c8] : make_uint4(0, 0, 0, 0);
        float4 a, b2;
        a.x = bf2f((ushort_t)(v.x & 0xFFFF)); a.y = bf2f((ushort_t)(v.x >> 16));
        a.z = bf2f((ushort_t)(v.y & 0xFFFF)); a.w = bf2f((ushort_t)(v.y >> 16));
        b2.x = bf2f((ushort_t)(v.z & 0xFFFF)); b2.y = bf2f((ushort_t)(v.z >> 16));
        b2.z = bf2f((ushort_t)(v.w & 0xFFFF)); b2.w = bf2f((ushort_t)(v.w >> 16));
        int sw = (r >> 2) & 15;
        Hl4[r * 16 + ((2 * c8 + 0) ^ sw)] = a;
        Hl4[r * 16 + ((2 * c8 + 1) ^ sw)] = b2;
    }
    __syncthreads();

    int tc = tid & 7, tr = tid >> 3;
    float4 acc0 = make_float4(0.f, 0.f, 0.f, 0.f);
    float4 acc1 = acc0, acc2 = acc0, acc3 = acc0;
    const float4* Wl4c = (const float4*)Wl;
    const float4* Hl4c = (const float4*)Hl;

#pragma unroll 4
    for (int kk = 0; kk < 16; ++kk) {
        int sw = kk ^ (tr & 15);
        float4 xv0 = Hl4c[(4 * tr + 0) * 16 + sw];
        float4 xv1 = Hl4c[(4 * tr + 1) * 16 + sw];
        float4 xv2 = Hl4c[(4 * tr + 2) * 16 + sw];
        float4 xv3 = Hl4c[(4 * tr + 3) * 16 + sw];
        float4 w0 = Wl4c[(4 * kk + 0) * 8 + tc];
        float4 w1 = Wl4c[(4 * kk + 1) * 8 + tc];
        float4 w2 = Wl4c[(4 * kk + 2) * 8 + tc];
        float4 w3 = Wl4c[(4 * kk + 3) * 8 + tc];
        fma4(acc0, xv0.x, w0); fma4(acc0, xv0.y, w1); fma4(acc0, xv0.z, w2); fma4(acc0, xv0.w, w3);
        fma4(acc1, xv1.x, w0); fma4(acc1, xv1.y, w1); fma4(acc1, xv1.z, w2); fma4(acc1, xv1.w, w3);
        fma4(acc2, xv2.x, w0); fma4(acc2, xv2.y, w1); fma4(acc2, xv2.z, w2); fma4(acc2, xv2.w, w3);
        fma4(acc3, xv3.x, w0); fma4(acc3, xv3.y, w1); fma4(acc3, xv3.z, w2); fma4(acc3, xv3.w, w3);
    }

    int gr = base + 4 * tr;
#pragma unroll
    for (int k = 0; k < 4; ++k) {
        int r = gr + k;
        if (r < N) {
            float d = dinv[r];
            float4 a = (k == 0) ? acc0 : (k == 1) ? acc1 : (k == 2) ? acc2 : acc3;
            ushort4 o = make_ushort4(f2bf(a.x * d), f2bf(a.y * d), f2bf(a.z * d), f2bf(a.w * d));
            *(ushort4*)(&hwb[(size_t)r * F2 + 4 * tc]) = o;
        }
    }
}

// ================= layer 2 aggregation + fused log_softmax =================
__global__ void agg2_lsm(const int* __restrict__ ptr, const int* __restrict__ erow,
                         const ushort_t* __restrict__ hwb, const float* __restrict__ dinv,
                         const float* __restrict__ b, float* __restrict__ out, int N) {
    int t = blockIdx.x * 256 + threadIdx.x;
    int i = t >> 5, j = t & 31;
    if (i >= N) return;
    float acc = bf2f(hwb[(size_t)i * F2 + j]);
    int e = ptr[i], end = ptr[i + 1];
    for (; e + 3 < end; e += 4) {
        int r0 = erow[e], r1 = erow[e + 1], r2 = erow[e + 2], r3 = erow[e + 3];
        float v0 = bf2f(hwb[(size_t)r0 * F2 + j]);
        float v1 = bf2f(hwb[(size_t)r1 * F2 + j]);
        float v2 = bf2f(hwb[(size_t)r2 * F2 + j]);
        float v3 = bf2f(hwb[(size_t)r3 * F2 + j]);
        acc += v0; acc += v1; acc += v2; acc += v3;
    }
    for (; e < end; ++e) acc += bf2f(hwb[(size_t)erow[e] * F2 + j]);
    acc = acc * dinv[i] + b[j];
    float m = acc;
    for (int off = 16; off; off >>= 1) m = fmaxf(m, __shfl_xor(m, off, 32));
    float s = expf(acc - m);
    for (int off = 16; off; off >>= 1) s += __shfl_xor(s, off, 32);
    out[(size_t)i * F2 + j] = acc - m - logf(s);
}

extern "C" void kernel_launch(void* const* d_in, const int* in_sizes, int n_in,
                              void* d_out, int out_size, void* d_ws, size_t ws_size,
                              hipStream_t stream) {
    const float* x  = (const float*)d_in[0];
    const int*   ei = (const int*)d_in[1];
    const float* W1 = (const float*)d_in[2];
    const float* b1 = (const float*)d_in[3];
    const float* W2 = (const float*)d_in[4];
    const float* b2 = (const float*)d_in[5];

    int N = in_sizes[0] / F0;
    int E = in_sizes[1] / 2;
    const int* row = ei;
    const int* col = ei + E;

    size_t Np = ((size_t)N + 63) & ~(size_t)63;
    size_t Ep = ((size_t)E + 63) & ~(size_t)63;
    int*      cnt     = (int*)d_ws;                  // Np (reused as cur)
    int*      ptr     = cnt + Np;                    // Np+64
    float*    dinv    = (float*)(ptr + Np + 64);     // Np
    int*      partial = (int*)(dinv + Np);           // 1024
    int*      erow    = partial + 1024;              // Ep
    ushort_t* xwb     = (ushort_t*)(erow + Ep);      // Np*64 bf16
    ushort_t* h1b     = xwb + Np * F1;               // Np*64 bf16
    ushort_t* hwb     = h1b + Np * F1;               // Np*32 bf16
    int*      cur     = cnt;
    float*    out2    = (float*)d_out;

    int nbN  = (N + 255) / 256;
    int nbN1 = (N + 256) / 256;
    int cpx  = (N + 7) / 8;   // cols per XCD range

    zero_cnt<<<nbN, 256, 0, stream>>>(cnt, N);
    count_deg<<<256 * 8, 256, 0, stream>>>(col, cnt, E, cpx);
    scan_partial<<<nbN, 256, 0, stream>>>(cnt, partial, N);
    scan_block<<<1, 1024, 0, stream>>>(partial, nbN);
    scan_final<<<nbN1, 256, 0, stream>>>(cnt, partial, ptr, cur, dinv, N, E);
    edge_fill<<<256 * 8, 256, 0, stream>>>(row, col, cur, erow, E, cpx);

    gemm1<<<(N + 63) / 64, 256, 0, stream>>>(x, W1, dinv, xwb, N);
    agg1<<<(int)(((size_t)N * F1 + 255) / 256), 256, 0, stream>>>(ptr, erow, xwb, dinv, b1, h1b, N);
    gemm2<<<(N + 127) / 128, 256, 0, stream>>>(h1b, W2, dinv, hwb, N);
    agg2_lsm<<<(int)(((size_t)N * F2 + 255) / 256), 256, 0, stream>>>(ptr, erow, hwb, dinv, b2, out2, N);
}

// Round 12
// 176.159 us; speedup vs baseline: 1.0576x; 1.0099x over previous
//
#include <hip/hip_runtime.h>

#define F0 128
#define F1 64
#define F2 32

typedef unsigned short ushort_t;
typedef unsigned int uint_t;

__device__ __forceinline__ ushort_t f2bf(float f) {   // f32 -> bf16 RNE
    uint_t u = __float_as_uint(f);
    return (ushort_t)((u + 0x7FFFu + ((u >> 16) & 1u)) >> 16);
}
__device__ __forceinline__ float bf2f(ushort_t u) {   // bf16 -> f32
    return __uint_as_float((uint_t)u << 16);
}

// ================= CSR build =================
__global__ void zero_cnt(int* __restrict__ cnt, int N) {
    int i = blockIdx.x * 256 + threadIdx.x;
    if (i < N) cnt[i] = 0;
}

// XCD-partitioned histogram, ONE edge-chunk per block (no serial loop):
// grid = nchunks*8; block b: partition b&7, chunk b>>3. Max atomic MLP.
__global__ void count_deg(const int* __restrict__ col, int* cnt, int E, int cpx) {
    int x = blockIdx.x & 7;
    int lo = x * cpx, hi = lo + cpx;
    int e = (blockIdx.x >> 3) * 256 + threadIdx.x;
    if (e < E) {
        int c = col[e];
        if (c >= lo && c < hi) atomicAdd(&cnt[c], 1);
    }
}

__global__ void scan_partial(const int* __restrict__ cnt, int* __restrict__ partial, int N) {
    __shared__ int red[256];
    int i = blockIdx.x * 256 + threadIdx.x;
    red[threadIdx.x] = (i < N) ? cnt[i] : 0;
    __syncthreads();
    for (int off = 128; off; off >>= 1) {
        if (threadIdx.x < off) red[threadIdx.x] += red[threadIdx.x + off];
        __syncthreads();
    }
    if (threadIdx.x == 0) partial[blockIdx.x] = red[0];
}

__global__ __launch_bounds__(1024) void scan_block(int* partial, int nb) {
    __shared__ int s[1024];
    int t = threadIdx.x;
    int v = (t < nb) ? partial[t] : 0;
    s[t] = v;
    __syncthreads();
    for (int off = 1; off < 1024; off <<= 1) {
        int u = (t >= off) ? s[t - off] : 0;
        __syncthreads();
        s[t] += u;
        __syncthreads();
    }
    if (t < nb) partial[t] = s[t] - v;
}

// cur may alias cnt: each element read once before any write.
__global__ void scan_final(const int* __restrict__ cnt, const int* __restrict__ partial,
                           int* __restrict__ ptr, int* __restrict__ cur,
                           float* __restrict__ dinv, int N, int E) {
    __shared__ int s[256];
    int t = threadIdx.x;
    int i = blockIdx.x * 256 + t;
    int v = (i < N) ? cnt[i] : 0;
    s[t] = v;
    __syncthreads();
    for (int off = 1; off < 256; off <<= 1) {
        int u = (t >= off) ? s[t - off] : 0;
        __syncthreads();
        s[t] += u;
        __syncthreads();
    }
    if (i < N) {
        int p = partial[blockIdx.x] + s[t] - v;
        ptr[i] = p;
        cur[i] = p;
        dinv[i] = rsqrtf((float)(v + 1));
    } else if (i == N) {
        ptr[N] = E;
    }
}

// XCD-partitioned counting-sort fill, ONE edge-chunk per block.
__global__ void edge_fill(const int* __restrict__ row, const int* __restrict__ col,
                          int* cur, int* __restrict__ erow, int E, int cpx) {
    int x = blockIdx.x & 7;
    int lo = x * cpx, hi = lo + cpx;
    int e = (blockIdx.x >> 3) * 256 + threadIdx.x;
    if (e < E) {
        int c = col[e];
        if (c >= lo && c < hi) {
            int pos = atomicAdd(&cur[c], 1);
            erow[pos] = row[e];
        }
    }
}

// ================= register-tiled GEMMs =================
__device__ __forceinline__ void fma4(float4& a, float xs, const float4& wv) {
    a.x = fmaf(xs, wv.x, a.x);
    a.y = fmaf(xs, wv.y, a.y);
    a.z = fmaf(xs, wv.z, a.z);
    a.w = fmaf(xs, wv.w, a.w);
}

// gemm1: xwb = (x @ W1) * dinv[row], stored bf16. tile 64x64, thread = 4x4.
__global__ __launch_bounds__(256) void gemm1(const float* __restrict__ x,
                                             const float* __restrict__ W,
                                             const float* __restrict__ dinv,
                                             ushort_t* __restrict__ xwb, int N) {
    __shared__ float Xl[64 * F0];   // 32KB, swizzled
    __shared__ float Wl[F0 * F1];   // 32KB, linear [k][64]
    int tid = threadIdx.x;
    int base = blockIdx.x * 64;

    const float4* W4 = (const float4*)W;
    float4* Wl4 = (float4*)Wl;
#pragma unroll
    for (int i = 0; i < 8; ++i) Wl4[tid + 256 * i] = W4[tid + 256 * i];

    float4* Xl4 = (float4*)Xl;
#pragma unroll
    for (int i = 0; i < 8; ++i) {
        int idx = tid + 256 * i;
        int r = idx >> 5, c4 = idx & 31;
        int gr = base + r;
        float4 v = (gr < N) ? ((const float4*)x)[(size_t)gr * 32 + c4]
                            : make_float4(0.f, 0.f, 0.f, 0.f);
        Xl4[r * 32 + (c4 ^ (r >> 2))] = v;
    }
    __syncthreads();

    int tc = tid & 15, tr = tid >> 4;
    float4 acc0 = make_float4(0.f, 0.f, 0.f, 0.f);
    float4 acc1 = acc0, acc2 = acc0, acc3 = acc0;
    const float4* Wl4c = (const float4*)Wl;
    const float4* Xl4c = (const float4*)Xl;

#pragma unroll 4
    for (int kk = 0; kk < 32; ++kk) {
        float4 xv0 = Xl4c[(4 * tr + 0) * 32 + (kk ^ tr)];
        float4 xv1 = Xl4c[(4 * tr + 1) * 32 + (kk ^ tr)];
        float4 xv2 = Xl4c[(4 * tr + 2) * 32 + (kk ^ tr)];
        float4 xv3 = Xl4c[(4 * tr + 3) * 32 + (kk ^ tr)];
        float4 w0 = Wl4c[(4 * kk + 0) * 16 + tc];
        float4 w1 = Wl4c[(4 * kk + 1) * 16 + tc];
        float4 w2 = Wl4c[(4 * kk + 2) * 16 + tc];
        float4 w3 = Wl4c[(4 * kk + 3) * 16 + tc];
        fma4(acc0, xv0.x, w0); fma4(acc0, xv0.y, w1); fma4(acc0, xv0.z, w2); fma4(acc0, xv0.w, w3);
        fma4(acc1, xv1.x, w0); fma4(acc1, xv1.y, w1); fma4(acc1, xv1.z, w2); fma4(acc1, xv1.w, w3);
        fma4(acc2, xv2.x, w0); fma4(acc2, xv2.y, w1); fma4(acc2, xv2.z, w2); fma4(acc2, xv2.w, w3);
        fma4(acc3, xv3.x, w0); fma4(acc3, xv3.y, w1); fma4(acc3, xv3.z, w2); fma4(acc3, xv3.w, w3);
    }

    int gr = base + 4 * tr;
#pragma unroll
    for (int k = 0; k < 4; ++k) {
        int r = gr + k;
        if (r < N) {
            float d = dinv[r];
            float4 a = (k == 0) ? acc0 : (k == 1) ? acc1 : (k == 2) ? acc2 : acc3;
            ushort4 o = make_ushort4(f2bf(a.x * d), f2bf(a.y * d), f2bf(a.z * d), f2bf(a.w * d));
            *(ushort4*)(&xwb[(size_t)r * F1 + 4 * tc]) = o;
        }
    }
}

// ================= layer 1 aggregation: one wave per node =================
// h1b[i] = bf16( relu( dinv[i]*(scaled[i] + sum_e scaled[row_e]) + b1 ) )
// int4 edge loads (align-peeled) + unroll 8 -> 8 gathers in flight.
__global__ void agg1(const int* __restrict__ ptr, const int* __restrict__ erow,
                     const ushort_t* __restrict__ xwb, const float* __restrict__ dinv,
                     const float* __restrict__ b, ushort_t* __restrict__ h1b, int N) {
    int t = blockIdx.x * 256 + threadIdx.x;
    int i = t >> 6, j = t & 63;
    if (i >= N) return;
    float acc = bf2f(xwb[(size_t)i * F1 + j]);   // scaled self term
    int e = ptr[i], end = ptr[i + 1];
    while (e < end && (e & 3)) {                 // peel to 16B alignment (wave-uniform)
        acc += bf2f(xwb[(size_t)erow[e] * F1 + j]);
        ++e;
    }
    for (; e + 7 < end; e += 8) {
        int4 a4 = *(const int4*)&erow[e];
        int4 b4 = *(const int4*)&erow[e + 4];
        float v0 = bf2f(xwb[(size_t)a4.x * F1 + j]);
        float v1 = bf2f(xwb[(size_t)a4.y * F1 + j]);
        float v2 = bf2f(xwb[(size_t)a4.z * F1 + j]);
        float v3 = bf2f(xwb[(size_t)a4.w * F1 + j]);
        float v4 = bf2f(xwb[(size_t)b4.x * F1 + j]);
        float v5 = bf2f(xwb[(size_t)b4.y * F1 + j]);
        float v6 = bf2f(xwb[(size_t)b4.z * F1 + j]);
        float v7 = bf2f(xwb[(size_t)b4.w * F1 + j]);
        acc += v0; acc += v1; acc += v2; acc += v3;
        acc += v4; acc += v5; acc += v6; acc += v7;
    }
    if (e + 3 < end) {
        int4 a4 = *(const int4*)&erow[e];
        acc += bf2f(xwb[(size_t)a4.x * F1 + j]);
        acc += bf2f(xwb[(size_t)a4.y * F1 + j]);
        acc += bf2f(xwb[(size_t)a4.z * F1 + j]);
        acc += bf2f(xwb[(size_t)a4.w * F1 + j]);
        e += 4;
    }
    for (; e < end; ++e) acc += bf2f(xwb[(size_t)erow[e] * F1 + j]);
    h1b[(size_t)i * F1 + j] = f2bf(fmaxf(acc * dinv[i] + b[j], 0.0f));
}

// gemm2: hwb = (h1b @ W2) * dinv[row], bf16 in / bf16 out. tile 128x32, 4x4.
__global__ __launch_bounds__(256) void gemm2(const ushort_t* __restrict__ h1b,
                                             const float* __restrict__ W,
                                             const float* __restrict__ dinv,
                                             ushort_t* __restrict__ hwb, int N) {
    __shared__ float Hl[128 * F1];  // 32KB, swizzled
    __shared__ float Wl[F1 * F2];   // 8KB
    int tid = threadIdx.x;
    int base = blockIdx.x * 128;

    const float4* W4 = (const float4*)W;
    float4* Wl4 = (float4*)Wl;
#pragma unroll
    for (int i = 0; i < 2; ++i) Wl4[tid + 256 * i] = W4[tid + 256 * i];

    const uint4* H4 = (const uint4*)h1b;
    float4* Hl4 = (float4*)Hl;
#pragma unroll
    for (int it = 0; it < 4; ++it) {
        int g = tid + 256 * it;          // 0..1023
        int r = g >> 3, c8 = g & 7;      // row 0..127, 8-elem group 0..7
        int gr = base + r;
        uint4 v = (gr < N) ? H4[(size_t)gr * 8 + c8] : make_uint4(0, 0, 0, 0);
        float4 a, b2;
        a.x = bf2f((ushort_t)(v.x & 0xFFFF)); a.y = bf2f((ushort_t)(v.x >> 16));
        a.z = bf2f((ushort_t)(v.y & 0xFFFF)); a.w = bf2f((ushort_t)(v.y >> 16));
        b2.x = bf2f((ushort_t)(v.z & 0xFFFF)); b2.y = bf2f((ushort_t)(v.z >> 16));
        b2.z = bf2f((ushort_t)(v.w & 0xFFFF)); b2.w = bf2f((ushort_t)(v.w >> 16));
        int sw = (r >> 2) & 15;
        Hl4[r * 16 + ((2 * c8 + 0) ^ sw)] = a;
        Hl4[r * 16 + ((2 * c8 + 1) ^ sw)] = b2;
    }
    __syncthreads();

    int tc = tid & 7, tr = tid >> 3;
    float4 acc0 = make_float4(0.f, 0.f, 0.f, 0.f);
    float4 acc1 = acc0, acc2 = acc0, acc3 = acc0;
    const float4* Wl4c = (const float4*)Wl;
    const float4* Hl4c = (const float4*)Hl;

#pragma unroll 4
    for (int kk = 0; kk < 16; ++kk) {
        int sw = kk ^ (tr & 15);
        float4 xv0 = Hl4c[(4 * tr + 0) * 16 + sw];
        float4 xv1 = Hl4c[(4 * tr + 1) * 16 + sw];
        float4 xv2 = Hl4c[(4 * tr + 2) * 16 + sw];
        float4 xv3 = Hl4c[(4 * tr + 3) * 16 + sw];
        float4 w0 = Wl4c[(4 * kk + 0) * 8 + tc];
        float4 w1 = Wl4c[(4 * kk + 1) * 8 + tc];
        float4 w2 = Wl4c[(4 * kk + 2) * 8 + tc];
        float4 w3 = Wl4c[(4 * kk + 3) * 8 + tc];
        fma4(acc0, xv0.x, w0); fma4(acc0, xv0.y, w1); fma4(acc0, xv0.z, w2); fma4(acc0, xv0.w, w3);
        fma4(acc1, xv1.x, w0); fma4(acc1, xv1.y, w1); fma4(acc1, xv1.z, w2); fma4(acc1, xv1.w, w3);
        fma4(acc2, xv2.x, w0); fma4(acc2, xv2.y, w1); fma4(acc2, xv2.z, w2); fma4(acc2, xv2.w, w3);
        fma4(acc3, xv3.x, w0); fma4(acc3, xv3.y, w1); fma4(acc3, xv3.z, w2); fma4(acc3, xv3.w, w3);
    }

    int gr = base + 4 * tr;
#pragma unroll
    for (int k = 0; k < 4; ++k) {
        int r = gr + k;
        if (r < N) {
            float d = dinv[r];
            float4 a = (k == 0) ? acc0 : (k == 1) ? acc1 : (k == 2) ? acc2 : acc3;
            ushort4 o = make_ushort4(f2bf(a.x * d), f2bf(a.y * d), f2bf(a.z * d), f2bf(a.w * d));
            *(ushort4*)(&hwb[(size_t)r * F2 + 4 * tc]) = o;
        }
    }
}

// ================= layer 2 aggregation + fused log_softmax =================
__global__ void agg2_lsm(const int* __restrict__ ptr, const int* __restrict__ erow,
                         const ushort_t* __restrict__ hwb, const float* __restrict__ dinv,
                         const float* __restrict__ b, float* __restrict__ out, int N) {
    int t = blockIdx.x * 256 + threadIdx.x;
    int i = t >> 5, j = t & 31;
    if (i >= N) return;
    float acc = bf2f(hwb[(size_t)i * F2 + j]);
    int e = ptr[i], end = ptr[i + 1];
    while (e < end && (e & 3)) {
        acc += bf2f(hwb[(size_t)erow[e] * F2 + j]);
        ++e;
    }
    for (; e + 7 < end; e += 8) {
        int4 a4 = *(const int4*)&erow[e];
        int4 b4 = *(const int4*)&erow[e + 4];
        float v0 = bf2f(hwb[(size_t)a4.x * F2 + j]);
        float v1 = bf2f(hwb[(size_t)a4.y * F2 + j]);
        float v2 = bf2f(hwb[(size_t)a4.z * F2 + j]);
        float v3 = bf2f(hwb[(size_t)a4.w * F2 + j]);
        float v4 = bf2f(hwb[(size_t)b4.x * F2 + j]);
        float v5 = bf2f(hwb[(size_t)b4.y * F2 + j]);
        float v6 = bf2f(hwb[(size_t)b4.z * F2 + j]);
        float v7 = bf2f(hwb[(size_t)b4.w * F2 + j]);
        acc += v0; acc += v1; acc += v2; acc += v3;
        acc += v4; acc += v5; acc += v6; acc += v7;
    }
    if (e + 3 < end) {
        int4 a4 = *(const int4*)&erow[e];
        acc += bf2f(hwb[(size_t)a4.x * F2 + j]);
        acc += bf2f(hwb[(size_t)a4.y * F2 + j]);
        acc += bf2f(hwb[(size_t)a4.z * F2 + j]);
        acc += bf2f(hwb[(size_t)a4.w * F2 + j]);
        e += 4;
    }
    for (; e < end; ++e) acc += bf2f(hwb[(size_t)erow[e] * F2 + j]);
    acc = acc * dinv[i] + b[j];
    float m = acc;
    for (int off = 16; off; off >>= 1) m = fmaxf(m, __shfl_xor(m, off, 32));
    float s = expf(acc - m);
    for (int off = 16; off; off >>= 1) s += __shfl_xor(s, off, 32);
    out[(size_t)i * F2 + j] = acc - m - logf(s);
}

extern "C" void kernel_launch(void* const* d_in, const int* in_sizes, int n_in,
                              void* d_out, int out_size, void* d_ws, size_t ws_size,
                              hipStream_t stream) {
    const float* x  = (const float*)d_in[0];
    const int*   ei = (const int*)d_in[1];
    const float* W1 = (const float*)d_in[2];
    const float* b1 = (const float*)d_in[3];
    const float* W2 = (const float*)d_in[4];
    const float* b2 = (const float*)d_in[5];

    int N = in_sizes[0] / F0;
    int E = in_sizes[1] / 2;
    const int* row = ei;
    const int* col = ei + E;

    size_t Np = ((size_t)N + 63) & ~(size_t)63;
    size_t Ep = ((size_t)E + 63) & ~(size_t)63;
    int*      cnt     = (int*)d_ws;                  // Np (reused as cur)
    int*      ptr     = cnt + Np;                    // Np+64
    float*    dinv    = (float*)(ptr + Np + 64);     // Np
    int*      partial = (int*)(dinv + Np);           // 1024
    int*      erow    = partial + 1024;              // Ep
    ushort_t* xwb     = (ushort_t*)(erow + Ep);      // Np*64 bf16
    ushort_t* h1b     = xwb + Np * F1;               // Np*64 bf16
    ushort_t* hwb     = h1b + Np * F1;               // Np*32 bf16
    int*      cur     = cnt;
    float*    out2    = (float*)d_out;

    int nbN  = (N + 255) / 256;
    int nbN1 = (N + 256) / 256;
    int nbE  = (E + 255) / 256;   // edge chunks (one per block-octet)
    int cpx  = (N + 7) / 8;       // cols per XCD range

    zero_cnt<<<nbN, 256, 0, stream>>>(cnt, N);
    count_deg<<<nbE * 8, 256, 0, stream>>>(col, cnt, E, cpx);
    scan_partial<<<nbN, 256, 0, stream>>>(cnt, partial, N);
    scan_block<<<1, 1024, 0, stream>>>(partial, nbN);
    scan_final<<<nbN1, 256, 0, stream>>>(cnt, partial, ptr, cur, dinv, N, E);
    edge_fill<<<nbE * 8, 256, 0, stream>>>(row, col, cur, erow, E, cpx);

    gemm1<<<(N + 63) / 64, 256, 0, stream>>>(x, W1, dinv, xwb, N);
    agg1<<<(int)(((size_t)N * F1 + 255) / 256), 256, 0, stream>>>(ptr, erow, xwb, dinv, b1, h1b, N);
    gemm2<<<(N + 127) / 128, 256, 0, stream>>>(h1b, W2, dinv, hwb, N);
    agg2_lsm<<<(int)(((size_t)N * F2 + 255) / 256), 256, 0, stream>>>(ptr, erow, hwb, dinv, b2, out2, N);
}

// Round 13
// 160.999 us; speedup vs baseline: 1.1571x; 1.0942x over previous
//
#include <hip/hip_runtime.h>

#define F0 128
#define F1 64
#define F2 32
#define CPB 256    // cols per bucket (bucket = col >> 8; requires N < 65536)
#define EPB 4096   // edges per coarse block

typedef unsigned short ushort_t;
typedef unsigned int uint_t;

__device__ __forceinline__ ushort_t f2bf(float f) {   // f32 -> bf16 RNE
    uint_t u = __float_as_uint(f);
    return (ushort_t)((u + 0x7FFFu + ((u >> 16) & 1u)) >> 16);
}
__device__ __forceinline__ float bf2f(ushort_t u) {   // bf16 -> f32
    return __uint_as_float((uint_t)u << 16);
}

// ================= CSR build =================
__global__ void zero_cnt(int* __restrict__ cnt, int N) {
    int i = blockIdx.x * 256 + threadIdx.x;
    if (i < N) cnt[i] = 0;
}

// XCD-partitioned one-shot histogram (r8/r11).
__global__ void count_deg(const int* __restrict__ col, int* cnt, int E, int cpx) {
    int x = blockIdx.x & 7;
    int lo = x * cpx, hi = lo + cpx;
    int e = (blockIdx.x >> 3) * 256 + threadIdx.x;
    if (e < E) {
        int c = col[e];
        if (c >= lo && c < hi) atomicAdd(&cnt[c], 1);
    }
}

__global__ void scan_partial(const int* __restrict__ cnt, int* __restrict__ partial, int N) {
    __shared__ int red[256];
    int i = blockIdx.x * 256 + threadIdx.x;
    red[threadIdx.x] = (i < N) ? cnt[i] : 0;
    __syncthreads();
    for (int off = 128; off; off >>= 1) {
        if (threadIdx.x < off) red[threadIdx.x] += red[threadIdx.x + off];
        __syncthreads();
    }
    if (threadIdx.x == 0) partial[blockIdx.x] = red[0];
}

__global__ __launch_bounds__(1024) void scan_block(int* partial, int nb) {
    __shared__ int s[1024];
    int t = threadIdx.x;
    int v = (t < nb) ? partial[t] : 0;
    s[t] = v;
    __syncthreads();
    for (int off = 1; off < 1024; off <<= 1) {
        int u = (t >= off) ? s[t - off] : 0;
        __syncthreads();
        s[t] += u;
        __syncthreads();
    }
    if (t < nb) partial[t] = s[t] - v;
}

// also seeds cur2[b] = ptr[b*CPB] for the coarse partition pass.
__global__ void scan_final(const int* __restrict__ cnt, const int* __restrict__ partial,
                           int* __restrict__ ptr, int* __restrict__ cur2,
                           float* __restrict__ dinv, int N, int E) {
    __shared__ int s[256];
    int t = threadIdx.x;
    int i = blockIdx.x * 256 + t;
    int v = (i < N) ? cnt[i] : 0;
    s[t] = v;
    __syncthreads();
    for (int off = 1; off < 256; off <<= 1) {
        int u = (t >= off) ? s[t - off] : 0;
        __syncthreads();
        s[t] += u;
        __syncthreads();
    }
    if (i < N) {
        int p = partial[blockIdx.x] + s[t] - v;
        ptr[i] = p;
        dinv[i] = rsqrtf((float)(v + 1));
        if ((i & (CPB - 1)) == 0) cur2[i >> 8] = p;   // bucket base
    } else if (i == N) {
        ptr[N] = E;
    }
}

// Phase 1: coarse partition into col-buckets. Per block: LDS stage + histogram,
// ONE global atomic per (block,bucket) to allocate a contiguous run, then
// coalesced-ish run writes. No per-edge returning atomics, no 4B scatters.
__global__ __launch_bounds__(256) void coarse_part(const int* __restrict__ row,
                                                   const int* __restrict__ col,
                                                   int* cur2, uint_t* __restrict__ ebuf,
                                                   int E) {
    __shared__ uint_t stage[EPB];   // 16KB packed edges
    __shared__ int hist[256];
    __shared__ int hbase[256];
    int t = threadIdx.x;
    int e0 = blockIdx.x * EPB;
    int cnt = E - e0; if (cnt > EPB) cnt = EPB;
    hist[t] = 0;
    __syncthreads();
    for (int k = t; k < cnt; k += 256) {
        int c = col[e0 + k], r = row[e0 + k];
        stage[k] = ((uint_t)r << 16) | (uint_t)c;
        atomicAdd(&hist[c >> 8], 1);
    }
    __syncthreads();
    int h = hist[t];
    if (h > 0) hbase[t] = atomicAdd(&cur2[t], h);
    __syncthreads();
    hist[t] = 0;   // reuse as local rank
    __syncthreads();
    for (int k = t; k < cnt; k += 256) {
        uint_t p = stage[k];
        int b = (int)((p & 0xFFFFu) >> 8);
        int rk = atomicAdd(&hist[b], 1);
        ebuf[hbase[b] + rk] = p;
    }
}

// Phase 2: exact placement within each bucket via LDS atomics. One block per
// bucket; every erow line written by exactly this block (no cross-CU churn).
__global__ __launch_bounds__(256) void fine_scatter(const int* __restrict__ ptr,
                                                    const uint_t* __restrict__ ebuf,
                                                    int* __restrict__ erow, int N) {
    __shared__ int curl[CPB];
    int b = blockIdx.x;
    int cbase = b << 8;
    int t = threadIdx.x;
    int cend = cbase + CPB; if (cend > N) cend = N;
    if (cbase + t < cend) curl[t] = ptr[cbase + t];
    int seg0 = ptr[cbase];
    int seg1 = ptr[cend];
    __syncthreads();
    for (int k = seg0 + t; k < seg1; k += 256) {
        uint_t p = ebuf[k];
        int c = (int)(p & 0xFFFFu);
        int r = (int)(p >> 16);
        int pos = atomicAdd(&curl[c - cbase], 1);
        erow[pos] = r;
    }
}

// ================= register-tiled GEMMs =================
__device__ __forceinline__ void fma4(float4& a, float xs, const float4& wv) {
    a.x = fmaf(xs, wv.x, a.x);
    a.y = fmaf(xs, wv.y, a.y);
    a.z = fmaf(xs, wv.z, a.z);
    a.w = fmaf(xs, wv.w, a.w);
}

// gemm1: xwb = (x @ W1) * dinv[row], stored bf16. tile 64x64, thread = 4x4.
__global__ __launch_bounds__(256) void gemm1(const float* __restrict__ x,
                                             const float* __restrict__ W,
                                             const float* __restrict__ dinv,
                                             ushort_t* __restrict__ xwb, int N) {
    __shared__ float Xl[64 * F0];   // 32KB, swizzled
    __shared__ float Wl[F0 * F1];   // 32KB, linear [k][64]
    int tid = threadIdx.x;
    int base = blockIdx.x * 64;

    const float4* W4 = (const float4*)W;
    float4* Wl4 = (float4*)Wl;
#pragma unroll
    for (int i = 0; i < 8; ++i) Wl4[tid + 256 * i] = W4[tid + 256 * i];

    float4* Xl4 = (float4*)Xl;
#pragma unroll
    for (int i = 0; i < 8; ++i) {
        int idx = tid + 256 * i;
        int r = idx >> 5, c4 = idx & 31;
        int gr = base + r;
        float4 v = (gr < N) ? ((const float4*)x)[(size_t)gr * 32 + c4]
                            : make_float4(0.f, 0.f, 0.f, 0.f);
        Xl4[r * 32 + (c4 ^ (r >> 2))] = v;
    }
    __syncthreads();

    int tc = tid & 15, tr = tid >> 4;
    float4 acc0 = make_float4(0.f, 0.f, 0.f, 0.f);
    float4 acc1 = acc0, acc2 = acc0, acc3 = acc0;
    const float4* Wl4c = (const float4*)Wl;
    const float4* Xl4c = (const float4*)Xl;

#pragma unroll 4
    for (int kk = 0; kk < 32; ++kk) {
        float4 xv0 = Xl4c[(4 * tr + 0) * 32 + (kk ^ tr)];
        float4 xv1 = Xl4c[(4 * tr + 1) * 32 + (kk ^ tr)];
        float4 xv2 = Xl4c[(4 * tr + 2) * 32 + (kk ^ tr)];
        float4 xv3 = Xl4c[(4 * tr + 3) * 32 + (kk ^ tr)];
        float4 w0 = Wl4c[(4 * kk + 0) * 16 + tc];
        float4 w1 = Wl4c[(4 * kk + 1) * 16 + tc];
        float4 w2 = Wl4c[(4 * kk + 2) * 16 + tc];
        float4 w3 = Wl4c[(4 * kk + 3) * 16 + tc];
        fma4(acc0, xv0.x, w0); fma4(acc0, xv0.y, w1); fma4(acc0, xv0.z, w2); fma4(acc0, xv0.w, w3);
        fma4(acc1, xv1.x, w0); fma4(acc1, xv1.y, w1); fma4(acc1, xv1.z, w2); fma4(acc1, xv1.w, w3);
        fma4(acc2, xv2.x, w0); fma4(acc2, xv2.y, w1); fma4(acc2, xv2.z, w2); fma4(acc2, xv2.w, w3);
        fma4(acc3, xv3.x, w0); fma4(acc3, xv3.y, w1); fma4(acc3, xv3.z, w2); fma4(acc3, xv3.w, w3);
    }

    int gr = base + 4 * tr;
#pragma unroll
    for (int k = 0; k < 4; ++k) {
        int r = gr + k;
        if (r < N) {
            float d = dinv[r];
            float4 a = (k == 0) ? acc0 : (k == 1) ? acc1 : (k == 2) ? acc2 : acc3;
            ushort4 o = make_ushort4(f2bf(a.x * d), f2bf(a.y * d), f2bf(a.z * d), f2bf(a.w * d));
            *(ushort4*)(&xwb[(size_t)r * F1 + 4 * tc]) = o;
        }
    }
}

// ================= layer 1 aggregation: one wave per node =================
__global__ void agg1(const int* __restrict__ ptr, const int* __restrict__ erow,
                     const ushort_t* __restrict__ xwb, const float* __restrict__ dinv,
                     const float* __restrict__ b, ushort_t* __restrict__ h1b, int N) {
    int t = blockIdx.x * 256 + threadIdx.x;
    int i = t >> 6, j = t & 63;
    if (i >= N) return;
    float acc = bf2f(xwb[(size_t)i * F1 + j]);   // scaled self term
    int e = ptr[i], end = ptr[i + 1];
    while (e < end && (e & 3)) {                 // peel to 16B alignment
        acc += bf2f(xwb[(size_t)erow[e] * F1 + j]);
        ++e;
    }
    for (; e + 7 < end; e += 8) {
        int4 a4 = *(const int4*)&erow[e];
        int4 b4 = *(const int4*)&erow[e + 4];
        float v0 = bf2f(xwb[(size_t)a4.x * F1 + j]);
        float v1 = bf2f(xwb[(size_t)a4.y * F1 + j]);
        float v2 = bf2f(xwb[(size_t)a4.z * F1 + j]);
        float v3 = bf2f(xwb[(size_t)a4.w * F1 + j]);
        float v4 = bf2f(xwb[(size_t)b4.x * F1 + j]);
        float v5 = bf2f(xwb[(size_t)b4.y * F1 + j]);
        float v6 = bf2f(xwb[(size_t)b4.z * F1 + j]);
        float v7 = bf2f(xwb[(size_t)b4.w * F1 + j]);
        acc += v0; acc += v1; acc += v2; acc += v3;
        acc += v4; acc += v5; acc += v6; acc += v7;
    }
    if (e + 3 < end) {
        int4 a4 = *(const int4*)&erow[e];
        acc += bf2f(xwb[(size_t)a4.x * F1 + j]);
        acc += bf2f(xwb[(size_t)a4.y * F1 + j]);
        acc += bf2f(xwb[(size_t)a4.z * F1 + j]);
        acc += bf2f(xwb[(size_t)a4.w * F1 + j]);
        e += 4;
    }
    for (; e < end; ++e) acc += bf2f(xwb[(size_t)erow[e] * F1 + j]);
    h1b[(size_t)i * F1 + j] = f2bf(fmaxf(acc * dinv[i] + b[j], 0.0f));
}

// gemm2: hwb = (h1b @ W2) * dinv[row], bf16 in / bf16 out. tile 128x32, 4x4.
__global__ __launch_bounds__(256) void gemm2(const ushort_t* __restrict__ h1b,
                                             const float* __restrict__ W,
                                             const float* __restrict__ dinv,
                                             ushort_t* __restrict__ hwb, int N) {
    __shared__ float Hl[128 * F1];  // 32KB, swizzled
    __shared__ float Wl[F1 * F2];   // 8KB
    int tid = threadIdx.x;
    int base = blockIdx.x * 128;

    const float4* W4 = (const float4*)W;
    float4* Wl4 = (float4*)Wl;
#pragma unroll
    for (int i = 0; i < 2; ++i) Wl4[tid + 256 * i] = W4[tid + 256 * i];

    const uint4* H4 = (const uint4*)h1b;
    float4* Hl4 = (float4*)Hl;
#pragma unroll
    for (int it = 0; it < 4; ++it) {
        int g = tid + 256 * it;
        int r = g >> 3, c8 = g & 7;
        int gr = base + r;
        uint4 v = (gr < N) ? H4[(size_t)gr * 8 + c8] : make_uint4(0, 0, 0, 0);
        float4 a, b2;
        a.x = bf2f((ushort_t)(v.x & 0xFFFF)); a.y = bf2f((ushort_t)(v.x >> 16));
        a.z = bf2f((ushort_t)(v.y & 0xFFFF)); a.w = bf2f((ushort_t)(v.y >> 16));
        b2.x = bf2f((ushort_t)(v.z & 0xFFFF)); b2.y = bf2f((ushort_t)(v.z >> 16));
        b2.z = bf2f((ushort_t)(v.w & 0xFFFF)); b2.w = bf2f((ushort_t)(v.w >> 16));
        int sw = (r >> 2) & 15;
        Hl4[r * 16 + ((2 * c8 + 0) ^ sw)] = a;
        Hl4[r * 16 + ((2 * c8 + 1) ^ sw)] = b2;
    }
    __syncthreads();

    int tc = tid & 7, tr = tid >> 3;
    float4 acc0 = make_float4(0.f, 0.f, 0.f, 0.f);
    float4 acc1 = acc0, acc2 = acc0, acc3 = acc0;
    const float4* Wl4c = (const float4*)Wl;
    const float4* Hl4c = (const float4*)Hl;

#pragma unroll 4
    for (int kk = 0; kk < 16; ++kk) {
        int sw = kk ^ (tr & 15);
        float4 xv0 = Hl4c[(4 * tr + 0) * 16 + sw];
        float4 xv1 = Hl4c[(4 * tr + 1) * 16 + sw];
        float4 xv2 = Hl4c[(4 * tr + 2) * 16 + sw];
        float4 xv3 = Hl4c[(4 * tr + 3) * 16 + sw];
        float4 w0 = Wl4c[(4 * kk + 0) * 8 + tc];
        float4 w1 = Wl4c[(4 * kk + 1) * 8 + tc];
        float4 w2 = Wl4c[(4 * kk + 2) * 8 + tc];
        float4 w3 = Wl4c[(4 * kk + 3) * 8 + tc];
        fma4(acc0, xv0.x, w0); fma4(acc0, xv0.y, w1); fma4(acc0, xv0.z, w2); fma4(acc0, xv0.w, w3);
        fma4(acc1, xv1.x, w0); fma4(acc1, xv1.y, w1); fma4(acc1, xv1.z, w2); fma4(acc1, xv1.w, w3);
        fma4(acc2, xv2.x, w0); fma4(acc2, xv2.y, w1); fma4(acc2, xv2.z, w2); fma4(acc2, xv2.w, w3);
        fma4(acc3, xv3.x, w0); fma4(acc3, xv3.y, w1); fma4(acc3, xv3.z, w2); fma4(acc3, xv3.w, w3);
    }

    int gr = base + 4 * tr;
#pragma unroll
    for (int k = 0; k < 4; ++k) {
        int r = gr + k;
        if (r < N) {
            float d = dinv[r];
            float4 a = (k == 0) ? acc0 : (k == 1) ? acc1 : (k == 2) ? acc2 : acc3;
            ushort4 o = make_ushort4(f2bf(a.x * d), f2bf(a.y * d), f2bf(a.z * d), f2bf(a.w * d));
            *(ushort4*)(&hwb[(size_t)r * F2 + 4 * tc]) = o;
        }
    }
}

// ================= layer 2 aggregation + fused log_softmax =================
__global__ void agg2_lsm(const int* __restrict__ ptr, const int* __restrict__ erow,
                         const ushort_t* __restrict__ hwb, const float* __restrict__ dinv,
                         const float* __restrict__ b, float* __restrict__ out, int N) {
    int t = blockIdx.x * 256 + threadIdx.x;
    int i = t >> 5, j = t & 31;
    if (i >= N) return;
    float acc = bf2f(hwb[(size_t)i * F2 + j]);
    int e = ptr[i], end = ptr[i + 1];
    while (e < end && (e & 3)) {
        acc += bf2f(hwb[(size_t)erow[e] * F2 + j]);
        ++e;
    }
    for (; e + 7 < end; e += 8) {
        int4 a4 = *(const int4*)&erow[e];
        int4 b4 = *(const int4*)&erow[e + 4];
        float v0 = bf2f(hwb[(size_t)a4.x * F2 + j]);
        float v1 = bf2f(hwb[(size_t)a4.y * F2 + j]);
        float v2 = bf2f(hwb[(size_t)a4.z * F2 + j]);
        float v3 = bf2f(hwb[(size_t)a4.w * F2 + j]);
        float v4 = bf2f(hwb[(size_t)b4.x * F2 + j]);
        float v5 = bf2f(hwb[(size_t)b4.y * F2 + j]);
        float v6 = bf2f(hwb[(size_t)b4.z * F2 + j]);
        float v7 = bf2f(hwb[(size_t)b4.w * F2 + j]);
        acc += v0; acc += v1; acc += v2; acc += v3;
        acc += v4; acc += v5; acc += v6; acc += v7;
    }
    if (e + 3 < end) {
        int4 a4 = *(const int4*)&erow[e];
        acc += bf2f(hwb[(size_t)a4.x * F2 + j]);
        acc += bf2f(hwb[(size_t)a4.y * F2 + j]);
        acc += bf2f(hwb[(size_t)a4.z * F2 + j]);
        acc += bf2f(hwb[(size_t)a4.w * F2 + j]);
        e += 4;
    }
    for (; e < end; ++e) acc += bf2f(hwb[(size_t)erow[e] * F2 + j]);
    acc = acc * dinv[i] + b[j];
    float m = acc;
    for (int off = 16; off; off >>= 1) m = fmaxf(m, __shfl_xor(m, off, 32));
    float s = expf(acc - m);
    for (int off = 16; off; off >>= 1) s += __shfl_xor(s, off, 32);
    out[(size_t)i * F2 + j] = acc - m - logf(s);
}

extern "C" void kernel_launch(void* const* d_in, const int* in_sizes, int n_in,
                              void* d_out, int out_size, void* d_ws, size_t ws_size,
                              hipStream_t stream) {
    const float* x  = (const float*)d_in[0];
    const int*   ei = (const int*)d_in[1];
    const float* W1 = (const float*)d_in[2];
    const float* b1 = (const float*)d_in[3];
    const float* W2 = (const float*)d_in[4];
    const float* b2 = (const float*)d_in[5];

    int N = in_sizes[0] / F0;
    int E = in_sizes[1] / 2;
    const int* row = ei;
    const int* col = ei + E;

    size_t Np = ((size_t)N + 63) & ~(size_t)63;
    size_t Ep = ((size_t)E + 63) & ~(size_t)63;
    int*      cnt     = (int*)d_ws;                  // Np
    int*      ptr     = cnt + Np;                    // Np+64
    float*    dinv    = (float*)(ptr + Np + 64);     // Np
    int*      partial = (int*)(dinv + Np);           // 1024
    int*      cur2    = partial + 1024;              // 256 bucket cursors
    int*      erow    = cur2 + 256;                  // Ep
    uint_t*   ebuf    = (uint_t*)(erow + Ep);        // Ep packed edges
    ushort_t* xwb     = (ushort_t*)(ebuf + Ep);      // Np*64 bf16
    ushort_t* h1b     = xwb + Np * F1;               // Np*64 bf16
    ushort_t* hwb     = h1b + Np * F1;               // Np*32 bf16
    float*    out2    = (float*)d_out;

    int nbN   = (N + 255) / 256;
    int nbN1  = (N + 256) / 256;
    int nbE   = (E + 255) / 256;
    int nbC   = (E + EPB - 1) / EPB;          // coarse blocks
    int nbuck = (N + CPB - 1) / CPB;          // buckets (= fine blocks)
    int cpx   = (N + 7) / 8;

    zero_cnt<<<nbN, 256, 0, stream>>>(cnt, N);
    count_deg<<<nbE * 8, 256, 0, stream>>>(col, cnt, E, cpx);
    scan_partial<<<nbN, 256, 0, stream>>>(cnt, partial, N);
    scan_block<<<1, 1024, 0, stream>>>(partial, nbN);
    scan_final<<<nbN1, 256, 0, stream>>>(cnt, partial, ptr, cur2, dinv, N, E);
    coarse_part<<<nbC, 256, 0, stream>>>(row, col, cur2, ebuf, E);
    fine_scatter<<<nbuck, 256, 0, stream>>>(ptr, ebuf, erow, N);

    gemm1<<<(N + 63) / 64, 256, 0, stream>>>(x, W1, dinv, xwb, N);
    agg1<<<(int)(((size_t)N * F1 + 255) / 256), 256, 0, stream>>>(ptr, erow, xwb, dinv, b1, h1b, N);
    gemm2<<<(N + 127) / 128, 256, 0, stream>>>(h1b, W2, dinv, hwb, N);
    agg2_lsm<<<(int)(((size_t)N * F2 + 255) / 256), 256, 0, stream>>>(ptr, erow, hwb, dinv, b2, out2, N);
}

// Round 14
// 129.113 us; speedup vs baseline: 1.4429x; 1.2470x over previous
//
#include <hip/hip_runtime.h>

#define F0 128
#define F1 64
#define F2 32
#define CPB 256    // cols per bucket (bucket = col >> 8; requires N < 65536)
#define EPB 4096   // edges per coarse block

typedef unsigned short ushort_t;
typedef unsigned int uint_t;

__device__ __forceinline__ ushort_t f2bf(float f) {   // f32 -> bf16 RNE
    uint_t u = __float_as_uint(f);
    return (ushort_t)((u + 0x7FFFu + ((u >> 16) & 1u)) >> 16);
}
__device__ __forceinline__ float bf2f(ushort_t u) {   // bf16 -> f32
    return __uint_as_float((uint_t)u << 16);
}

// ================= CSR build (bucket-level front-end) =================
__global__ void zero_b(int* __restrict__ bcnt) {
    bcnt[threadIdx.x] = 0;
}

// per-block LDS histogram of buckets, 256 global atomics per block
__global__ __launch_bounds__(256) void bucket_count(const int* __restrict__ col,
                                                    int* __restrict__ bcnt, int E) {
    __shared__ int h[256];
    int t = threadIdx.x;
    h[t] = 0;
    __syncthreads();
    int e0 = blockIdx.x * EPB;
    int cnt = E - e0; if (cnt > EPB) cnt = EPB;
    for (int k = t; k < cnt; k += 256) atomicAdd(&h[col[e0 + k] >> 8], 1);
    __syncthreads();
    if (h[t]) atomicAdd(&bcnt[t], h[t]);
}

// single block: exclusive scan of 256 bucket counts -> bucket_base, cur2
__global__ __launch_bounds__(256) void bucket_scan(const int* __restrict__ bcnt,
                                                   int* __restrict__ bucket_base,
                                                   int* __restrict__ cur2) {
    __shared__ int s[256];
    int t = threadIdx.x;
    int v = bcnt[t];
    s[t] = v;
    __syncthreads();
    for (int off = 1; off < 256; off <<= 1) {
        int u = (t >= off) ? s[t - off] : 0;
        __syncthreads();
        s[t] += u;
        __syncthreads();
    }
    int p = s[t] - v;   // exclusive
    bucket_base[t] = p;
    cur2[t] = p;
}

// Phase 1: coarse partition into col-buckets (r13 win). Per block: LDS stage +
// histogram, ONE global atomic per (block,bucket) to allocate a run, write runs.
__global__ __launch_bounds__(256) void coarse_part(const int* __restrict__ row,
                                                   const int* __restrict__ col,
                                                   int* cur2, uint_t* __restrict__ ebuf,
                                                   int E) {
    __shared__ uint_t stage[EPB];   // 16KB packed edges
    __shared__ int hist[256];
    __shared__ int hbase[256];
    int t = threadIdx.x;
    int e0 = blockIdx.x * EPB;
    int cnt = E - e0; if (cnt > EPB) cnt = EPB;
    hist[t] = 0;
    __syncthreads();
    for (int k = t; k < cnt; k += 256) {
        int c = col[e0 + k], r = row[e0 + k];
        stage[k] = ((uint_t)r << 16) | (uint_t)c;
        atomicAdd(&hist[c >> 8], 1);
    }
    __syncthreads();
    int h = hist[t];
    if (h > 0) hbase[t] = atomicAdd(&cur2[t], h);
    __syncthreads();
    hist[t] = 0;   // reuse as local rank
    __syncthreads();
    for (int k = t; k < cnt; k += 256) {
        uint_t p = stage[k];
        int b = (int)((p & 0xFFFFu) >> 8);
        int rk = atomicAdd(&hist[b], 1);
        ebuf[hbase[b] + rk] = p;
    }
}

// Phase 2: per bucket, build the N-wide CSR locally: LDS per-col histogram of
// the segment -> LDS scan -> write ptr/dinv for this bucket's 256 cols, then
// exact-place erow via LDS cursors. All erow lines single-writer.
__global__ __launch_bounds__(256) void fine_build(const int* __restrict__ bucket_base,
                                                  const uint_t* __restrict__ ebuf,
                                                  int* __restrict__ ptr,
                                                  float* __restrict__ dinv,
                                                  int* __restrict__ erow,
                                                  int N, int E, int nbuck) {
    __shared__ int hist[CPB];
    __shared__ int pref[CPB];
    int b = blockIdx.x;
    int cbase = b << 8;
    int t = threadIdx.x;
    int seg0 = bucket_base[b];
    int seg1 = (b + 1 < nbuck) ? bucket_base[b + 1] : E;
    hist[t] = 0;
    __syncthreads();
    for (int k = seg0 + t; k < seg1; k += 256)
        atomicAdd(&hist[ebuf[k] & 255u], 1);
    __syncthreads();
    int deg = hist[t];
    pref[t] = deg;
    __syncthreads();
    for (int off = 1; off < 256; off <<= 1) {   // Hillis-Steele inclusive
        int u = (t >= off) ? pref[t - off] : 0;
        __syncthreads();
        pref[t] += u;
        __syncthreads();
    }
    int base = seg0 + pref[t] - deg;            // exclusive prefix
    int c = cbase + t;
    if (c < N) {
        ptr[c] = base;
        dinv[c] = rsqrtf((float)(deg + 1));     // +1 self-loop
    }
    if (b == nbuck - 1 && t == 0) ptr[N] = E;
    __syncthreads();
    pref[t] = base;                             // reuse as cursor
    __syncthreads();
    for (int k = seg0 + t; k < seg1; k += 256) {
        uint_t p = ebuf[k];
        int pos = atomicAdd(&pref[p & 255u], 1);
        erow[pos] = (int)(p >> 16);
    }
}

// ================= register-tiled GEMMs =================
__device__ __forceinline__ void fma4(float4& a, float xs, const float4& wv) {
    a.x = fmaf(xs, wv.x, a.x);
    a.y = fmaf(xs, wv.y, a.y);
    a.z = fmaf(xs, wv.z, a.z);
    a.w = fmaf(xs, wv.w, a.w);
}

// gemm1: xwb = (x @ W1) * dinv[row], stored bf16. tile 64x64, thread = 4x4.
__global__ __launch_bounds__(256) void gemm1(const float* __restrict__ x,
                                             const float* __restrict__ W,
                                             const float* __restrict__ dinv,
                                             ushort_t* __restrict__ xwb, int N) {
    __shared__ float Xl[64 * F0];   // 32KB, swizzled
    __shared__ float Wl[F0 * F1];   // 32KB, linear [k][64]
    int tid = threadIdx.x;
    int base = blockIdx.x * 64;

    const float4* W4 = (const float4*)W;
    float4* Wl4 = (float4*)Wl;
#pragma unroll
    for (int i = 0; i < 8; ++i) Wl4[tid + 256 * i] = W4[tid + 256 * i];

    float4* Xl4 = (float4*)Xl;
#pragma unroll
    for (int i = 0; i < 8; ++i) {
        int idx = tid + 256 * i;
        int r = idx >> 5, c4 = idx & 31;
        int gr = base + r;
        float4 v = (gr < N) ? ((const float4*)x)[(size_t)gr * 32 + c4]
                            : make_float4(0.f, 0.f, 0.f, 0.f);
        Xl4[r * 32 + (c4 ^ (r >> 2))] = v;
    }
    __syncthreads();

    int tc = tid & 15, tr = tid >> 4;
    float4 acc0 = make_float4(0.f, 0.f, 0.f, 0.f);
    float4 acc1 = acc0, acc2 = acc0, acc3 = acc0;
    const float4* Wl4c = (const float4*)Wl;
    const float4* Xl4c = (const float4*)Xl;

#pragma unroll 4
    for (int kk = 0; kk < 32; ++kk) {
        float4 xv0 = Xl4c[(4 * tr + 0) * 32 + (kk ^ tr)];
        float4 xv1 = Xl4c[(4 * tr + 1) * 32 + (kk ^ tr)];
        float4 xv2 = Xl4c[(4 * tr + 2) * 32 + (kk ^ tr)];
        float4 xv3 = Xl4c[(4 * tr + 3) * 32 + (kk ^ tr)];
        float4 w0 = Wl4c[(4 * kk + 0) * 16 + tc];
        float4 w1 = Wl4c[(4 * kk + 1) * 16 + tc];
        float4 w2 = Wl4c[(4 * kk + 2) * 16 + tc];
        float4 w3 = Wl4c[(4 * kk + 3) * 16 + tc];
        fma4(acc0, xv0.x, w0); fma4(acc0, xv0.y, w1); fma4(acc0, xv0.z, w2); fma4(acc0, xv0.w, w3);
        fma4(acc1, xv1.x, w0); fma4(acc1, xv1.y, w1); fma4(acc1, xv1.z, w2); fma4(acc1, xv1.w, w3);
        fma4(acc2, xv2.x, w0); fma4(acc2, xv2.y, w1); fma4(acc2, xv2.z, w2); fma4(acc2, xv2.w, w3);
        fma4(acc3, xv3.x, w0); fma4(acc3, xv3.y, w1); fma4(acc3, xv3.z, w2); fma4(acc3, xv3.w, w3);
    }

    int gr = base + 4 * tr;
#pragma unroll
    for (int k = 0; k < 4; ++k) {
        int r = gr + k;
        if (r < N) {
            float d = dinv[r];
            float4 a = (k == 0) ? acc0 : (k == 1) ? acc1 : (k == 2) ? acc2 : acc3;
            ushort4 o = make_ushort4(f2bf(a.x * d), f2bf(a.y * d), f2bf(a.z * d), f2bf(a.w * d));
            *(ushort4*)(&xwb[(size_t)r * F1 + 4 * tc]) = o;
        }
    }
}

// ================= layer 1 aggregation: one wave per node =================
__global__ void agg1(const int* __restrict__ ptr, const int* __restrict__ erow,
                     const ushort_t* __restrict__ xwb, const float* __restrict__ dinv,
                     const float* __restrict__ b, ushort_t* __restrict__ h1b, int N) {
    int t = blockIdx.x * 256 + threadIdx.x;
    int i = t >> 6, j = t & 63;
    if (i >= N) return;
    float acc = bf2f(xwb[(size_t)i * F1 + j]);   // scaled self term
    int e = ptr[i], end = ptr[i + 1];
    while (e < end && (e & 3)) {                 // peel to 16B alignment
        acc += bf2f(xwb[(size_t)erow[e] * F1 + j]);
        ++e;
    }
    for (; e + 7 < end; e += 8) {
        int4 a4 = *(const int4*)&erow[e];
        int4 b4 = *(const int4*)&erow[e + 4];
        float v0 = bf2f(xwb[(size_t)a4.x * F1 + j]);
        float v1 = bf2f(xwb[(size_t)a4.y * F1 + j]);
        float v2 = bf2f(xwb[(size_t)a4.z * F1 + j]);
        float v3 = bf2f(xwb[(size_t)a4.w * F1 + j]);
        float v4 = bf2f(xwb[(size_t)b4.x * F1 + j]);
        float v5 = bf2f(xwb[(size_t)b4.y * F1 + j]);
        float v6 = bf2f(xwb[(size_t)b4.z * F1 + j]);
        float v7 = bf2f(xwb[(size_t)b4.w * F1 + j]);
        acc += v0; acc += v1; acc += v2; acc += v3;
        acc += v4; acc += v5; acc += v6; acc += v7;
    }
    if (e + 3 < end) {
        int4 a4 = *(const int4*)&erow[e];
        acc += bf2f(xwb[(size_t)a4.x * F1 + j]);
        acc += bf2f(xwb[(size_t)a4.y * F1 + j]);
        acc += bf2f(xwb[(size_t)a4.z * F1 + j]);
        acc += bf2f(xwb[(size_t)a4.w * F1 + j]);
        e += 4;
    }
    for (; e < end; ++e) acc += bf2f(xwb[(size_t)erow[e] * F1 + j]);
    h1b[(size_t)i * F1 + j] = f2bf(fmaxf(acc * dinv[i] + b[j], 0.0f));
}

// gemm2: hwb = (h1b @ W2) * dinv[row], bf16 in / bf16 out. tile 128x32, 4x4.
__global__ __launch_bounds__(256) void gemm2(const ushort_t* __restrict__ h1b,
                                             const float* __restrict__ W,
                                             const float* __restrict__ dinv,
                                             ushort_t* __restrict__ hwb, int N) {
    __shared__ float Hl[128 * F1];  // 32KB, swizzled
    __shared__ float Wl[F1 * F2];   // 8KB
    int tid = threadIdx.x;
    int base = blockIdx.x * 128;

    const float4* W4 = (const float4*)W;
    float4* Wl4 = (float4*)Wl;
#pragma unroll
    for (int i = 0; i < 2; ++i) Wl4[tid + 256 * i] = W4[tid + 256 * i];

    const uint4* H4 = (const uint4*)h1b;
    float4* Hl4 = (float4*)Hl;
#pragma unroll
    for (int it = 0; it < 4; ++it) {
        int g = tid + 256 * it;
        int r = g >> 3, c8 = g & 7;
        int gr = base + r;
        uint4 v = (gr < N) ? H4[(size_t)gr * 8 + c8] : make_uint4(0, 0, 0, 0);
        float4 a, b2;
        a.x = bf2f((ushort_t)(v.x & 0xFFFF)); a.y = bf2f((ushort_t)(v.x >> 16));
        a.z = bf2f((ushort_t)(v.y & 0xFFFF)); a.w = bf2f((ushort_t)(v.y >> 16));
        b2.x = bf2f((ushort_t)(v.z & 0xFFFF)); b2.y = bf2f((ushort_t)(v.z >> 16));
        b2.z = bf2f((ushort_t)(v.w & 0xFFFF)); b2.w = bf2f((ushort_t)(v.w >> 16));
        int sw = (r >> 2) & 15;
        Hl4[r * 16 + ((2 * c8 + 0) ^ sw)] = a;
        Hl4[r * 16 + ((2 * c8 + 1) ^ sw)] = b2;
    }
    __syncthreads();

    int tc = tid & 7, tr = tid >> 3;
    float4 acc0 = make_float4(0.f, 0.f, 0.f, 0.f);
    float4 acc1 = acc0, acc2 = acc0, acc3 = acc0;
    const float4* Wl4c = (const float4*)Wl;
    const float4* Hl4c = (const float4*)Hl;

#pragma unroll 4
    for (int kk = 0; kk < 16; ++kk) {
        int sw = kk ^ (tr & 15);
        float4 xv0 = Hl4c[(4 * tr + 0) * 16 + sw];
        float4 xv1 = Hl4c[(4 * tr + 1) * 16 + sw];
        float4 xv2 = Hl4c[(4 * tr + 2) * 16 + sw];
        float4 xv3 = Hl4c[(4 * tr + 3) * 16 + sw];
        float4 w0 = Wl4c[(4 * kk + 0) * 8 + tc];
        float4 w1 = Wl4c[(4 * kk + 1) * 8 + tc];
        float4 w2 = Wl4c[(4 * kk + 2) * 8 + tc];
        float4 w3 = Wl4c[(4 * kk + 3) * 8 + tc];
        fma4(acc0, xv0.x, w0); fma4(acc0, xv0.y, w1); fma4(acc0, xv0.z, w2); fma4(acc0, xv0.w, w3);
        fma4(acc1, xv1.x, w0); fma4(acc1, xv1.y, w1); fma4(acc1, xv1.z, w2); fma4(acc1, xv1.w, w3);
        fma4(acc2, xv2.x, w0); fma4(acc2, xv2.y, w1); fma4(acc2, xv2.z, w2); fma4(acc2, xv2.w, w3);
        fma4(acc3, xv3.x, w0); fma4(acc3, xv3.y, w1); fma4(acc3, xv3.z, w2); fma4(acc3, xv3.w, w3);
    }

    int gr = base + 4 * tr;
#pragma unroll
    for (int k = 0; k < 4; ++k) {
        int r = gr + k;
        if (r < N) {
            float d = dinv[r];
            float4 a = (k == 0) ? acc0 : (k == 1) ? acc1 : (k == 2) ? acc2 : acc3;
            ushort4 o = make_ushort4(f2bf(a.x * d), f2bf(a.y * d), f2bf(a.z * d), f2bf(a.w * d));
            *(ushort4*)(&hwb[(size_t)r * F2 + 4 * tc]) = o;
        }
    }
}

// ================= layer 2 aggregation + fused log_softmax =================
__global__ void agg2_lsm(const int* __restrict__ ptr, const int* __restrict__ erow,
                         const ushort_t* __restrict__ hwb, const float* __restrict__ dinv,
                         const float* __restrict__ b, float* __restrict__ out, int N) {
    int t = blockIdx.x * 256 + threadIdx.x;
    int i = t >> 5, j = t & 31;
    if (i >= N) return;
    float acc = bf2f(hwb[(size_t)i * F2 + j]);
    int e = ptr[i], end = ptr[i + 1];
    while (e < end && (e & 3)) {
        acc += bf2f(hwb[(size_t)erow[e] * F2 + j]);
        ++e;
    }
    for (; e + 7 < end; e += 8) {
        int4 a4 = *(const int4*)&erow[e];
        int4 b4 = *(const int4*)&erow[e + 4];
        float v0 = bf2f(hwb[(size_t)a4.x * F2 + j]);
        float v1 = bf2f(hwb[(size_t)a4.y * F2 + j]);
        float v2 = bf2f(hwb[(size_t)a4.z * F2 + j]);
        float v3 = bf2f(hwb[(size_t)a4.w * F2 + j]);
        float v4 = bf2f(hwb[(size_t)b4.x * F2 + j]);
        float v5 = bf2f(hwb[(size_t)b4.y * F2 + j]);
        float v6 = bf2f(hwb[(size_t)b4.z * F2 + j]);
        float v7 = bf2f(hwb[(size_t)b4.w * F2 + j]);
        acc += v0; acc += v1; acc += v2; acc += v3;
        acc += v4; acc += v5; acc += v6; acc += v7;
    }
    if (e + 3 < end) {
        int4 a4 = *(const int4*)&erow[e];
        acc += bf2f(hwb[(size_t)a4.x * F2 + j]);
        acc += bf2f(hwb[(size_t)a4.y * F2 + j]);
        acc += bf2f(hwb[(size_t)a4.z * F2 + j]);
        acc += bf2f(hwb[(size_t)a4.w * F2 + j]);
        e += 4;
    }
    for (; e < end; ++e) acc += bf2f(hwb[(size_t)erow[e] * F2 + j]);
    acc = acc * dinv[i] + b[j];
    float m = acc;
    for (int off = 16; off; off >>= 1) m = fmaxf(m, __shfl_xor(m, off, 32));
    float s = expf(acc - m);
    for (int off = 16; off; off >>= 1) s += __shfl_xor(s, off, 32);
    out[(size_t)i * F2 + j] = acc - m - logf(s);
}

extern "C" void kernel_launch(void* const* d_in, const int* in_sizes, int n_in,
                              void* d_out, int out_size, void* d_ws, size_t ws_size,
                              hipStream_t stream) {
    const float* x  = (const float*)d_in[0];
    const int*   ei = (const int*)d_in[1];
    const float* W1 = (const float*)d_in[2];
    const float* b1 = (const float*)d_in[3];
    const float* W2 = (const float*)d_in[4];
    const float* b2 = (const float*)d_in[5];

    int N = in_sizes[0] / F0;
    int E = in_sizes[1] / 2;
    const int* row = ei;
    const int* col = ei + E;

    size_t Np = ((size_t)N + 63) & ~(size_t)63;
    size_t Ep = ((size_t)E + 63) & ~(size_t)63;
    int*      bcnt        = (int*)d_ws;                  // 256
    int*      bucket_base = bcnt + 256;                  // 256
    int*      cur2        = bucket_base + 256;           // 256
    int*      ptr         = cur2 + 256 + 64;             // Np+64
    float*    dinv        = (float*)(ptr + Np + 64);     // Np
    int*      erow        = (int*)(dinv + Np);           // Ep
    uint_t*   ebuf        = (uint_t*)(erow + Ep);        // Ep packed edges
    ushort_t* xwb         = (ushort_t*)(ebuf + Ep);      // Np*64 bf16
    ushort_t* h1b         = xwb + Np * F1;               // Np*64 bf16
    ushort_t* hwb         = h1b + Np * F1;               // Np*32 bf16
    float*    out2        = (float*)d_out;

    int nbC   = (E + EPB - 1) / EPB;          // edge chunks
    int nbuck = (N + CPB - 1) / CPB;          // buckets

    zero_b<<<1, 256, 0, stream>>>(bcnt);
    bucket_count<<<nbC, 256, 0, stream>>>(col, bcnt, E);
    bucket_scan<<<1, 256, 0, stream>>>(bcnt, bucket_base, cur2);
    coarse_part<<<nbC, 256, 0, stream>>>(row, col, cur2, ebuf, E);
    fine_build<<<nbuck, 256, 0, stream>>>(bucket_base, ebuf, ptr, dinv, erow, N, E, nbuck);

    gemm1<<<(N + 63) / 64, 256, 0, stream>>>(x, W1, dinv, xwb, N);
    agg1<<<(int)(((size_t)N * F1 + 255) / 256), 256, 0, stream>>>(ptr, erow, xwb, dinv, b1, h1b, N);
    gemm2<<<(N + 127) / 128, 256, 0, stream>>>(h1b, W2, dinv, hwb, N);
    agg2_lsm<<<(int)(((size_t)N * F2 + 255) / 256), 256, 0, stream>>>(ptr, erow, hwb, dinv, b2, out2, N);
}

// Round 15
// 120.913 us; speedup vs baseline: 1.5408x; 1.0678x over previous
//
#include <hip/hip_runtime.h>

#define F0 128
#define F1 64
#define F2 32
#define CPB 256    // cols per bucket (bucket = col >> 8; requires N < 65536)
#define EPB 4096   // edges per coarse block

typedef unsigned short ushort_t;
typedef unsigned int uint_t;

__device__ __forceinline__ ushort_t f2bf(float f) {   // f32 -> bf16 RNE
    uint_t u = __float_as_uint(f);
    return (ushort_t)((u + 0x7FFFu + ((u >> 16) & 1u)) >> 16);
}
__device__ __forceinline__ float bf2f(ushort_t u) {   // bf16 -> f32
    return __uint_as_float((uint_t)u << 16);
}
__device__ __forceinline__ float bflo(uint_t v) { return __uint_as_float(v << 16); }
__device__ __forceinline__ float bfhi(uint_t v) { return __uint_as_float(v & 0xFFFF0000u); }

// ================= CSR build (bucket-level front-end) =================
__global__ void zero_b(int* __restrict__ bcnt) {
    bcnt[threadIdx.x] = 0;
}

__global__ __launch_bounds__(256) void bucket_count(const int* __restrict__ col,
                                                    int* __restrict__ bcnt, int E) {
    __shared__ int h[256];
    int t = threadIdx.x;
    h[t] = 0;
    __syncthreads();
    int e0 = blockIdx.x * EPB;
    int cnt = E - e0; if (cnt > EPB) cnt = EPB;
    for (int k = t; k < cnt; k += 256) atomicAdd(&h[col[e0 + k] >> 8], 1);
    __syncthreads();
    if (h[t]) atomicAdd(&bcnt[t], h[t]);
}

__global__ __launch_bounds__(256) void bucket_scan(const int* __restrict__ bcnt,
                                                   int* __restrict__ bucket_base,
                                                   int* __restrict__ cur2) {
    __shared__ int s[256];
    int t = threadIdx.x;
    int v = bcnt[t];
    s[t] = v;
    __syncthreads();
    for (int off = 1; off < 256; off <<= 1) {
        int u = (t >= off) ? s[t - off] : 0;
        __syncthreads();
        s[t] += u;
        __syncthreads();
    }
    int p = s[t] - v;   // exclusive
    bucket_base[t] = p;
    cur2[t] = p;
}

// Phase 1: coarse partition into col-buckets (r13 win).
__global__ __launch_bounds__(256) void coarse_part(const int* __restrict__ row,
                                                   const int* __restrict__ col,
                                                   int* cur2, uint_t* __restrict__ ebuf,
                                                   int E) {
    __shared__ uint_t stage[EPB];   // 16KB packed edges
    __shared__ int hist[256];
    __shared__ int hbase[256];
    int t = threadIdx.x;
    int e0 = blockIdx.x * EPB;
    int cnt = E - e0; if (cnt > EPB) cnt = EPB;
    hist[t] = 0;
    __syncthreads();
    for (int k = t; k < cnt; k += 256) {
        int c = col[e0 + k], r = row[e0 + k];
        stage[k] = ((uint_t)r << 16) | (uint_t)c;
        atomicAdd(&hist[c >> 8], 1);
    }
    __syncthreads();
    int h = hist[t];
    if (h > 0) hbase[t] = atomicAdd(&cur2[t], h);
    __syncthreads();
    hist[t] = 0;   // reuse as local rank
    __syncthreads();
    for (int k = t; k < cnt; k += 256) {
        uint_t p = stage[k];
        int b = (int)((p & 0xFFFFu) >> 8);
        int rk = atomicAdd(&hist[b], 1);
        ebuf[hbase[b] + rk] = p;
    }
}

// Phase 2: per bucket build ptr/dinv + place erow16 (ushort rows).
__global__ __launch_bounds__(256) void fine_build(const int* __restrict__ bucket_base,
                                                  const uint_t* __restrict__ ebuf,
                                                  int* __restrict__ ptr,
                                                  float* __restrict__ dinv,
                                                  ushort_t* __restrict__ erow,
                                                  int N, int E, int nbuck) {
    __shared__ int hist[CPB];
    __shared__ int pref[CPB];
    int b = blockIdx.x;
    int cbase = b << 8;
    int t = threadIdx.x;
    int seg0 = bucket_base[b];
    int seg1 = (b + 1 < nbuck) ? bucket_base[b + 1] : E;
    hist[t] = 0;
    __syncthreads();
    for (int k = seg0 + t; k < seg1; k += 256)
        atomicAdd(&hist[ebuf[k] & 255u], 1);
    __syncthreads();
    int deg = hist[t];
    pref[t] = deg;
    __syncthreads();
    for (int off = 1; off < 256; off <<= 1) {
        int u = (t >= off) ? pref[t - off] : 0;
        __syncthreads();
        pref[t] += u;
        __syncthreads();
    }
    int base = seg0 + pref[t] - deg;
    int c = cbase + t;
    if (c < N) {
        ptr[c] = base;
        dinv[c] = rsqrtf((float)(deg + 1));
    }
    if (b == nbuck - 1 && t == 0) ptr[N] = E;
    __syncthreads();
    pref[t] = base;    // reuse as cursor
    __syncthreads();
    for (int k = seg0 + t; k < seg1; k += 256) {
        uint_t p = ebuf[k];
        int pos = atomicAdd(&pref[p & 255u], 1);
        erow[pos] = (ushort_t)(p >> 16);
    }
}

// ================= register-tiled GEMMs =================
__device__ __forceinline__ void fma4(float4& a, float xs, const float4& wv) {
    a.x = fmaf(xs, wv.x, a.x);
    a.y = fmaf(xs, wv.y, a.y);
    a.z = fmaf(xs, wv.z, a.z);
    a.w = fmaf(xs, wv.w, a.w);
}

// gemm1: xwb = (x @ W1) * dinv[row], stored bf16. tile 64x64, thread = 4x4.
__global__ __launch_bounds__(256) void gemm1(const float* __restrict__ x,
                                             const float* __restrict__ W,
                                             const float* __restrict__ dinv,
                                             ushort_t* __restrict__ xwb, int N) {
    __shared__ float Xl[64 * F0];   // 32KB, swizzled
    __shared__ float Wl[F0 * F1];   // 32KB, linear [k][64]
    int tid = threadIdx.x;
    int base = blockIdx.x * 64;

    const float4* W4 = (const float4*)W;
    float4* Wl4 = (float4*)Wl;
#pragma unroll
    for (int i = 0; i < 8; ++i) Wl4[tid + 256 * i] = W4[tid + 256 * i];

    float4* Xl4 = (float4*)Xl;
#pragma unroll
    for (int i = 0; i < 8; ++i) {
        int idx = tid + 256 * i;
        int r = idx >> 5, c4 = idx & 31;
        int gr = base + r;
        float4 v = (gr < N) ? ((const float4*)x)[(size_t)gr * 32 + c4]
                            : make_float4(0.f, 0.f, 0.f, 0.f);
        Xl4[r * 32 + (c4 ^ (r >> 2))] = v;
    }
    __syncthreads();

    int tc = tid & 15, tr = tid >> 4;
    float4 acc0 = make_float4(0.f, 0.f, 0.f, 0.f);
    float4 acc1 = acc0, acc2 = acc0, acc3 = acc0;
    const float4* Wl4c = (const float4*)Wl;
    const float4* Xl4c = (const float4*)Xl;

#pragma unroll 4
    for (int kk = 0; kk < 32; ++kk) {
        float4 xv0 = Xl4c[(4 * tr + 0) * 32 + (kk ^ tr)];
        float4 xv1 = Xl4c[(4 * tr + 1) * 32 + (kk ^ tr)];
        float4 xv2 = Xl4c[(4 * tr + 2) * 32 + (kk ^ tr)];
        float4 xv3 = Xl4c[(4 * tr + 3) * 32 + (kk ^ tr)];
        float4 w0 = Wl4c[(4 * kk + 0) * 16 + tc];
        float4 w1 = Wl4c[(4 * kk + 1) * 16 + tc];
        float4 w2 = Wl4c[(4 * kk + 2) * 16 + tc];
        float4 w3 = Wl4c[(4 * kk + 3) * 16 + tc];
        fma4(acc0, xv0.x, w0); fma4(acc0, xv0.y, w1); fma4(acc0, xv0.z, w2); fma4(acc0, xv0.w, w3);
        fma4(acc1, xv1.x, w0); fma4(acc1, xv1.y, w1); fma4(acc1, xv1.z, w2); fma4(acc1, xv1.w, w3);
        fma4(acc2, xv2.x, w0); fma4(acc2, xv2.y, w1); fma4(acc2, xv2.z, w2); fma4(acc2, xv2.w, w3);
        fma4(acc3, xv3.x, w0); fma4(acc3, xv3.y, w1); fma4(acc3, xv3.z, w2); fma4(acc3, xv3.w, w3);
    }

    int gr = base + 4 * tr;
#pragma unroll
    for (int k = 0; k < 4; ++k) {
        int r = gr + k;
        if (r < N) {
            float d = dinv[r];
            float4 a = (k == 0) ? acc0 : (k == 1) ? acc1 : (k == 2) ? acc2 : acc3;
            ushort4 o = make_ushort4(f2bf(a.x * d), f2bf(a.y * d), f2bf(a.z * d), f2bf(a.w * d));
            *(ushort4*)(&xwb[(size_t)r * F1 + 4 * tc]) = o;
        }
    }
}

// ================= layer 1 aggregation: one wave per node, 2 edges/request ===
// lane = 32*h + l2: half h processes even/odd edges, lane covers features
// {2*l2, 2*l2+1} via uint loads (2 bf16). shfl_down(32) merges halves.
__global__ void agg1(const int* __restrict__ ptr, const ushort_t* __restrict__ erow,
                     const ushort_t* __restrict__ xwb, const float* __restrict__ dinv,
                     const float* __restrict__ b, ushort_t* __restrict__ h1b, int N) {
    int t = blockIdx.x * 256 + threadIdx.x;
    int i = t >> 6;
    if (i >= N) return;
    int l = t & 63, h = l >> 5, l2 = l & 31;
    const uint_t* xwb2 = (const uint_t*)xwb;

    float a0 = 0.f, a1 = 0.f;
    int e = ptr[i], end = ptr[i + 1];
    for (; e + 7 < end; e += 8) {
        int r0 = erow[e + 0 + h], r1 = erow[e + 2 + h];
        int r2 = erow[e + 4 + h], r3 = erow[e + 6 + h];
        uint_t v0 = xwb2[(size_t)r0 * 32 + l2];
        uint_t v1 = xwb2[(size_t)r1 * 32 + l2];
        uint_t v2 = xwb2[(size_t)r2 * 32 + l2];
        uint_t v3 = xwb2[(size_t)r3 * 32 + l2];
        a0 += bflo(v0); a1 += bfhi(v0);
        a0 += bflo(v1); a1 += bfhi(v1);
        a0 += bflo(v2); a1 += bfhi(v2);
        a0 += bflo(v3); a1 += bfhi(v3);
    }
    for (; e + 1 < end; e += 2) {
        int r0 = erow[e + h];
        uint_t v0 = xwb2[(size_t)r0 * 32 + l2];
        a0 += bflo(v0); a1 += bfhi(v0);
    }
    if (e < end && h == 0) {            // odd leftover: half 0 only
        uint_t v0 = xwb2[(size_t)erow[e] * 32 + l2];
        a0 += bflo(v0); a1 += bfhi(v0);
    }
    a0 += __shfl_down(a0, 32, 64);      // merge halves into lanes 0..31
    a1 += __shfl_down(a1, 32, 64);
    if (h == 0) {
        uint_t sv = xwb2[(size_t)i * 32 + l2];    // scaled self term
        a0 += bflo(sv); a1 += bfhi(sv);
        float d = dinv[i];
        float2 bb = ((const float2*)b)[l2];
        a0 = fmaxf(a0 * d + bb.x, 0.f);
        a1 = fmaxf(a1 * d + bb.y, 0.f);
        ((uint_t*)h1b)[(size_t)i * 32 + l2] = (uint_t)f2bf(a0) | ((uint_t)f2bf(a1) << 16);
    }
}

// gemm2: hwb = (h1b @ W2) * dinv[row], bf16 in / bf16 out. tile 128x32, 4x4.
__global__ __launch_bounds__(256) void gemm2(const ushort_t* __restrict__ h1b,
                                             const float* __restrict__ W,
                                             const float* __restrict__ dinv,
                                             ushort_t* __restrict__ hwb, int N) {
    __shared__ float Hl[128 * F1];  // 32KB, swizzled
    __shared__ float Wl[F1 * F2];   // 8KB
    int tid = threadIdx.x;
    int base = blockIdx.x * 128;

    const float4* W4 = (const float4*)W;
    float4* Wl4 = (float4*)Wl;
#pragma unroll
    for (int i = 0; i < 2; ++i) Wl4[tid + 256 * i] = W4[tid + 256 * i];

    const uint4* H4 = (const uint4*)h1b;
    float4* Hl4 = (float4*)Hl;
#pragma unroll
    for (int it = 0; it < 4; ++it) {
        int g = tid + 256 * it;
        int r = g >> 3, c8 = g & 7;
        int gr = base + r;
        uint4 v = (gr < N) ? H4[(size_t)gr * 8 + c8] : make_uint4(0, 0, 0, 0);
        float4 a, b2;
        a.x = bflo(v.x); a.y = bfhi(v.x);
        a.z = bflo(v.y); a.w = bfhi(v.y);
        b2.x = bflo(v.z); b2.y = bfhi(v.z);
        b2.z = bflo(v.w); b2.w = bfhi(v.w);
        int sw = (r >> 2) & 15;
        Hl4[r * 16 + ((2 * c8 + 0) ^ sw)] = a;
        Hl4[r * 16 + ((2 * c8 + 1) ^ sw)] = b2;
    }
    __syncthreads();

    int tc = tid & 7, tr = tid >> 3;
    float4 acc0 = make_float4(0.f, 0.f, 0.f, 0.f);
    float4 acc1 = acc0, acc2 = acc0, acc3 = acc0;
    const float4* Wl4c = (const float4*)Wl;
    const float4* Hl4c = (const float4*)Hl;

#pragma unroll 4
    for (int kk = 0; kk < 16; ++kk) {
        int sw = kk ^ (tr & 15);
        float4 xv0 = Hl4c[(4 * tr + 0) * 16 + sw];
        float4 xv1 = Hl4c[(4 * tr + 1) * 16 + sw];
        float4 xv2 = Hl4c[(4 * tr + 2) * 16 + sw];
        float4 xv3 = Hl4c[(4 * tr + 3) * 16 + sw];
        float4 w0 = Wl4c[(4 * kk + 0) * 8 + tc];
        float4 w1 = Wl4c[(4 * kk + 1) * 8 + tc];
        float4 w2 = Wl4c[(4 * kk + 2) * 8 + tc];
        float4 w3 = Wl4c[(4 * kk + 3) * 8 + tc];
        fma4(acc0, xv0.x, w0); fma4(acc0, xv0.y, w1); fma4(acc0, xv0.z, w2); fma4(acc0, xv0.w, w3);
        fma4(acc1, xv1.x, w0); fma4(acc1, xv1.y, w1); fma4(acc1, xv1.z, w2); fma4(acc1, xv1.w, w3);
        fma4(acc2, xv2.x, w0); fma4(acc2, xv2.y, w1); fma4(acc2, xv2.z, w2); fma4(acc2, xv2.w, w3);
        fma4(acc3, xv3.x, w0); fma4(acc3, xv3.y, w1); fma4(acc3, xv3.z, w2); fma4(acc3, xv3.w, w3);
    }

    int gr = base + 4 * tr;
#pragma unroll
    for (int k = 0; k < 4; ++k) {
        int r = gr + k;
        if (r < N) {
            float d = dinv[r];
            float4 a = (k == 0) ? acc0 : (k == 1) ? acc1 : (k == 2) ? acc2 : acc3;
            ushort4 o = make_ushort4(f2bf(a.x * d), f2bf(a.y * d), f2bf(a.z * d), f2bf(a.w * d));
            *(ushort4*)(&hwb[(size_t)r * F2 + 4 * tc]) = o;
        }
    }
}

// ================= layer 2 aggregation + fused log_softmax =================
// 32-lane group per node: g = lane&31 = 16*h + l2; lane covers features
// {2*l2, 2*l2+1}; shfl_down(16,32) merges edge-slots; LSM over 16 lanes.
__global__ void agg2_lsm(const int* __restrict__ ptr, const ushort_t* __restrict__ erow,
                         const ushort_t* __restrict__ hwb, const float* __restrict__ dinv,
                         const float* __restrict__ b, float* __restrict__ out, int N) {
    int t = blockIdx.x * 256 + threadIdx.x;
    int i = t >> 5;
    if (i >= N) return;
    int g = t & 31, h = g >> 4, l2 = g & 15;
    const uint_t* hwb2 = (const uint_t*)hwb;

    float a0 = 0.f, a1 = 0.f;
    int e = ptr[i], end = ptr[i + 1];
    for (; e + 7 < end; e += 8) {
        int r0 = erow[e + 0 + h], r1 = erow[e + 2 + h];
        int r2 = erow[e + 4 + h], r3 = erow[e + 6 + h];
        uint_t v0 = hwb2[(size_t)r0 * 16 + l2];
        uint_t v1 = hwb2[(size_t)r1 * 16 + l2];
        uint_t v2 = hwb2[(size_t)r2 * 16 + l2];
        uint_t v3 = hwb2[(size_t)r3 * 16 + l2];
        a0 += bflo(v0); a1 += bfhi(v0);
        a0 += bflo(v1); a1 += bfhi(v1);
        a0 += bflo(v2); a1 += bfhi(v2);
        a0 += bflo(v3); a1 += bfhi(v3);
    }
    for (; e + 1 < end; e += 2) {
        int r0 = erow[e + h];
        uint_t v0 = hwb2[(size_t)r0 * 16 + l2];
        a0 += bflo(v0); a1 += bfhi(v0);
    }
    if (e < end && h == 0) {
        uint_t v0 = hwb2[(size_t)erow[e] * 16 + l2];
        a0 += bflo(v0); a1 += bfhi(v0);
    }
    a0 += __shfl_down(a0, 16, 32);     // merge slots into lanes (g<16)
    a1 += __shfl_down(a1, 16, 32);

    uint_t sv = hwb2[(size_t)i * 16 + l2];
    a0 += bflo(sv); a1 += bfhi(sv);
    float d = dinv[i];
    float2 bb = ((const float2*)b)[l2];
    a0 = a0 * d + bb.x;
    a1 = a1 * d + bb.y;

    float m = fmaxf(a0, a1);
    for (int off = 8; off; off >>= 1) m = fmaxf(m, __shfl_xor(m, off, 16));
    float s = expf(a0 - m) + expf(a1 - m);
    for (int off = 8; off; off >>= 1) s += __shfl_xor(s, off, 16);
    float ls = logf(s);
    if (h == 0)
        ((float2*)out)[(size_t)i * 16 + l2] = make_float2(a0 - m - ls, a1 - m - ls);
}

extern "C" void kernel_launch(void* const* d_in, const int* in_sizes, int n_in,
                              void* d_out, int out_size, void* d_ws, size_t ws_size,
                              hipStream_t stream) {
    const float* x  = (const float*)d_in[0];
    const int*   ei = (const int*)d_in[1];
    const float* W1 = (const float*)d_in[2];
    const float* b1 = (const float*)d_in[3];
    const float* W2 = (const float*)d_in[4];
    const float* b2 = (const float*)d_in[5];

    int N = in_sizes[0] / F0;
    int E = in_sizes[1] / 2;
    const int* row = ei;
    const int* col = ei + E;

    size_t Np = ((size_t)N + 63) & ~(size_t)63;
    size_t Ep = ((size_t)E + 63) & ~(size_t)63;
    int*      bcnt        = (int*)d_ws;                  // 256
    int*      bucket_base = bcnt + 256;                  // 256
    int*      cur2        = bucket_base + 256;           // 256
    int*      ptr         = cur2 + 256 + 64;             // Np+64
    float*    dinv        = (float*)(ptr + Np + 64);     // Np
    ushort_t* erow        = (ushort_t*)(dinv + Np);      // Ep ushorts
    uint_t*   ebuf        = (uint_t*)(erow + Ep);        // Ep packed edges
    ushort_t* xwb         = (ushort_t*)(ebuf + Ep);      // Np*64 bf16
    ushort_t* h1b         = xwb + Np * F1;               // Np*64 bf16
    ushort_t* hwb         = h1b + Np * F1;               // Np*32 bf16
    float*    out2        = (float*)d_out;

    int nbC   = (E + EPB - 1) / EPB;          // edge chunks
    int nbuck = (N + CPB - 1) / CPB;          // buckets

    zero_b<<<1, 256, 0, stream>>>(bcnt);
    bucket_count<<<nbC, 256, 0, stream>>>(col, bcnt, E);
    bucket_scan<<<1, 256, 0, stream>>>(bcnt, bucket_base, cur2);
    coarse_part<<<nbC, 256, 0, stream>>>(row, col, cur2, ebuf, E);
    fine_build<<<nbuck, 256, 0, stream>>>(bucket_base, ebuf, ptr, dinv, erow, N, E, nbuck);

    gemm1<<<(N + 63) / 64, 256, 0, stream>>>(x, W1, dinv, xwb, N);
    agg1<<<(int)(((size_t)N * 64 + 255) / 256), 256, 0, stream>>>(ptr, erow, xwb, dinv, b1, h1b, N);
    gemm2<<<(N + 127) / 128, 256, 0, stream>>>(h1b, W2, dinv, hwb, N);
    agg2_lsm<<<(int)(((size_t)N * 32 + 255) / 256), 256, 0, stream>>>(ptr, erow, hwb, dinv, b2, out2, N);
}